// Round 5
// baseline (1907.351 us; speedup 1.0000x reference)
//
#include <hip/hip_runtime.h>
#include <hip/hip_cooperative_groups.h>
#include <math.h>

namespace cg = cooperative_groups;

#define NN 6000
#define EE 100000
#define ELL (EE + NN)   // edges + self loops for GAT

// ============================ Kernel 1: CSR + weight prep ====================
// S0: zero deg/cnt + compute W0 and packed Wcat; S1: deg/cnt; S2: scan; S3: fill
__global__ void __launch_bounds__(256) k_csr(
    const int* __restrict__ ei, const int* __restrict__ et,
    int* __restrict__ deg, float* __restrict__ cnt,
    int* __restrict__ rowptr, int* __restrict__ cursor, int* __restrict__ eids,
    const float* __restrict__ basis0, const float* __restrict__ comp0,
    const float* __restrict__ wb1, const float* __restrict__ wc1, const float* __restrict__ wr1,
    const float* __restrict__ wb2, const float* __restrict__ wc2, const float* __restrict__ wr2,
    const float* __restrict__ wb3, const float* __restrict__ wc3, const float* __restrict__ wr3,
    float* __restrict__ W0, float* __restrict__ Wcat){
  cg::grid_group g = cg::this_grid();
  const int gtid = blockIdx.x*256 + threadIdx.x;
  const int gsz  = gridDim.x*256;

  // ---- S0: zero deg (NN ints) + cnt (2NN floats, zero bits) ----
  for (int i = gtid; i < 3*NN; i += gsz) deg[i] = 0;   // deg then cnt contiguous
  // ---- S0b: weight prep ----
  for (int t0 = gtid; t0 < 2*NN*32 + 24576; t0 += gsz){
    if (t0 < 2*NN*32){
      int r = t0 / (NN*32);
      int no = t0 - r*(NN*32);
      float acc = 0.f;
      #pragma unroll
      for (int b=0;b<4;b++) acc += comp0[r*4+b] * basis0[b*(NN*32)+no];
      W0[t0] = acc;
    } else {
      int tw = t0 - 2*NN*32;
      const float *bb,*cc,*rr; int I,O; int t = tw;
      if (tw < 6144)        { bb=wb1;cc=wc1;rr=wr1;I=32;O=64; }
      else if (tw < 18432)  { bb=wb2;cc=wc2;rr=wr2;I=64;O=64; t -= 6144; }
      else                  { bb=wb3;cc=wc3;rr=wr3;I=64;O=32; t -= 18432; }
      int C = 3*O;
      int i = t / C; int col = t - i*C;
      float v;
      if (col < O) v = rr[i*O + col];
      else {
        int r = (col - O) / O; int o = col - O - r*O;
        v = 0.f;
        #pragma unroll
        for (int b=0;b<4;b++) v += cc[r*4+b]*bb[(b*I+i)*O + o];
      }
      Wcat[tw] = v;
    }
  }
  g.sync();

  // ---- S1: degrees + per-relation counts ----
  for (int j = gtid; j < ELL; j += gsz){
    if (j < EE){
      int d = ei[EE+j]; int r = et[j];
      atomicAdd(&deg[d], 1);
      atomicAdd(&cnt[r*NN+d], 1.0f);
    } else {
      atomicAdd(&deg[j-EE], 1);
    }
  }
  g.sync();

  // ---- S2: exclusive scan (block 0 only) ----
  __shared__ int ssum[256];
  if (blockIdx.x == 0){
    const int PER = 24; // 256*24 = 6144 >= 6000
    int tid = threadIdx.x;
    int base = tid*PER;
    int local[PER];
    int s = 0;
    #pragma unroll
    for (int k=0;k<PER;k++){ int i = base+k; int v = (i<NN)?deg[i]:0; local[k]=s; s+=v; }
    ssum[tid] = s; __syncthreads();
    for (int off=1; off<256; off<<=1){
      int v = (tid>=off) ? ssum[tid-off] : 0;
      __syncthreads();
      ssum[tid] += v;
      __syncthreads();
    }
    int prefix = (tid==0) ? 0 : ssum[tid-1];
    #pragma unroll
    for (int k=0;k<PER;k++){
      int i = base+k;
      if (i<NN){ int v = prefix+local[k]; rowptr[i]=v; cursor[i]=v; }
    }
    if (tid==255) rowptr[NN] = ssum[255];
  }
  g.sync();

  // ---- S3: fill CSR ----
  for (int j = gtid; j < ELL; j += gsz){
    int d = (j < EE) ? ei[EE + j] : (j - EE);
    int pos = atomicAdd(&cursor[d], 1);
    eids[pos] = j;
  }
}

// ============================ Kernel 2: full RGCN stack ======================
template<int I, int O>
__device__ __forceinline__ void nodemm_stage(const float* __restrict__ x,
                                             const float* __restrict__ Wc,
                                             float* __restrict__ H,
                                             int gtid, int gsz){
  const int C = 3*O;
  for (int t = gtid; t < NN*C; t += gsz){
    int n = t / C; int c = t - n*C;
    float acc = 0.f;
    #pragma unroll 8
    for (int i=0;i<I;i++) acc += x[n*I+i]*Wc[i*C+c];
    H[t] = acc;
  }
}

template<int O>
__device__ __forceinline__ void ragg_stage(const float* __restrict__ H,
                                           const float* __restrict__ rbias,
                                           const int* __restrict__ rowptr, const int* __restrict__ eids,
                                           const int* __restrict__ ei, const int* __restrict__ et,
                                           const float* __restrict__ cnt, float* __restrict__ xout,
                                           int gtid, int gsz){
  for (int idx = gtid; idx < NN*O; idx += gsz){
    int n = idx / O, o = idx - (idx/O)*O;
    int r0 = rowptr[n], r1 = rowptr[n+1];
    float a0 = 0.f, a1 = 0.f;
    for (int j=r0;j<r1;j++){
      int jj = eids[j];
      if (jj >= EE) continue;
      int s = ei[jj]; int r = et[jj];
      float v = H[s*3*O + O + r*O + o];
      if (r==0) a0 += v; else a1 += v;
    }
    float v = H[n*3*O + o] + rbias[o]
            + a0/fmaxf(cnt[n],1.f) + a1/fmaxf(cnt[NN+n],1.f);
    xout[n*O+o] = tanhf(v);
  }
}

__global__ void __launch_bounds__(256) k_rgcn(
    const float* __restrict__ W0, const float* __restrict__ root0,
    const float* __restrict__ rbias0, const float* __restrict__ Wcat,
    const float* __restrict__ rb1, const float* __restrict__ rb2, const float* __restrict__ rb3,
    const int* __restrict__ rowptr, const int* __restrict__ eids,
    const int* __restrict__ ei, const int* __restrict__ et,
    const float* __restrict__ cnt, float* __restrict__ xa, float* __restrict__ xb,
    float* __restrict__ H){
  cg::grid_group g = cg::this_grid();
  const int gtid = blockIdx.x*256 + threadIdx.x;
  const int gsz  = gridDim.x*256;

  // S0: layer 0 (x = I): gather W0 rows + root + tanh -> xa
  for (int idx = gtid; idx < NN*32; idx += gsz){
    int n = idx >> 5, o = idx & 31;
    int r0 = rowptr[n], r1 = rowptr[n+1];
    float a0 = 0.f, a1 = 0.f;
    for (int j=r0;j<r1;j++){
      int jj = eids[j];
      if (jj >= EE) continue;
      int s = ei[jj]; int r = et[jj];
      float v = W0[(r*NN + s)*32 + o];
      if (r==0) a0 += v; else a1 += v;
    }
    float v = root0[n*32+o] + rbias0[o]
            + a0/fmaxf(cnt[n],1.f) + a1/fmaxf(cnt[NN+n],1.f);
    xa[n*32+o] = tanhf(v);
  }
  g.sync();
  nodemm_stage<32,64>(xa, Wcat,         H, gtid, gsz);  g.sync();
  ragg_stage<64>(H, rb1, rowptr, eids, ei, et, cnt, xb, gtid, gsz); g.sync();
  nodemm_stage<64,64>(xb, Wcat + 6144,  H, gtid, gsz);  g.sync();
  ragg_stage<64>(H, rb2, rowptr, eids, ei, et, cnt, xa, gtid, gsz); g.sync();
  nodemm_stage<64,32>(xa, Wcat + 18432, H, gtid, gsz);  g.sync();
  ragg_stage<32>(H, rb3, rowptr, eids, ei, et, cnt, xb, gtid, gsz);
  // final RGCN output in xb (N x 32)
}

// ============================ Kernel 3: GAT ==================================
__global__ void __launch_bounds__(256) k_gat(
    const float* __restrict__ x, const float* __restrict__ gw,
    const float* __restrict__ as_, const float* __restrict__ ad_,
    const float* __restrict__ gat_b,
    const int* __restrict__ rowptr, const int* __restrict__ eids,
    const int* __restrict__ ei,
    float* __restrict__ h, float* __restrict__ asv, float* __restrict__ adv,
    float* __restrict__ coef, float* __restrict__ gout){
  cg::grid_group g = cg::this_grid();
  const int gtid = blockIdx.x*256 + threadIdx.x;
  const int gsz  = gridDim.x*256;
  __shared__ float sx[256];   // 8 nodes x 32

  // S0: h = x @ gw, 8 nodes per tile
  for (int tile = blockIdx.x; tile < NN/8; tile += gridDim.x){
    __syncthreads();
    sx[threadIdx.x] = x[tile*256 + threadIdx.x];
    __syncthreads();
    int c2 = threadIdx.x*2;
    float2 acc[8];
    #pragma unroll
    for (int k=0;k<8;k++) acc[k] = {0.f,0.f};
    for (int i=0;i<32;i++){
      const float2 gv = *(const float2*)&gw[i*512 + c2];
      #pragma unroll
      for (int k=0;k<8;k++){
        float xv = sx[k*32+i];
        acc[k].x += xv*gv.x; acc[k].y += xv*gv.y;
      }
    }
    #pragma unroll
    for (int k=0;k<8;k++) *(float2*)&h[(tile*8+k)*512 + c2] = acc[k];
  }
  g.sync();

  // S1: per-node attention scores (one wave per node)
  {
    int wid = gtid >> 6, lane = gtid & 63, nw = gsz >> 6;
    const float4* a4 = (const float4*)as_;
    const float4* d4 = (const float4*)ad_;
    for (int n = wid; n < NN; n += nw){
      const float4* hp = (const float4*)&h[n*512];
      float4 h0 = hp[lane*2], h1 = hp[lane*2+1];
      float4 A0 = a4[lane*2], A1 = a4[lane*2+1];
      float4 D0 = d4[lane*2], D1 = d4[lane*2+1];
      float sa = h0.x*A0.x+h0.y*A0.y+h0.z*A0.z+h0.w*A0.w
               + h1.x*A1.x+h1.y*A1.y+h1.z*A1.z+h1.w*A1.w;
      float sd = h0.x*D0.x+h0.y*D0.y+h0.z*D0.z+h0.w*D0.w
               + h1.x*D1.x+h1.y*D1.y+h1.z*D1.z+h1.w*D1.w;
      #pragma unroll
      for (int m=32;m>0;m>>=1){ sa += __shfl_xor(sa,m,64); sd += __shfl_xor(sd,m,64); }
      if (lane==0){ asv[n]=sa; adv[n]=sd; }
    }
  }
  g.sync();

  // S2: per-node softmax over incident edges
  {
    int wid = gtid >> 6, lane = gtid & 63, nw = gsz >> 6;
    for (int n = wid; n < NN; n += nw){
      int r0 = rowptr[n], r1 = rowptr[n+1];
      float advn = adv[n];
      float m = -1e30f;
      for (int j=r0+lane; j<r1; j+=64){
        int jj = eids[j]; int s = (jj<EE)? ei[jj] : jj-EE;
        float a = asv[s] + advn; a = (a>=0.f)? a : 0.2f*a;
        m = fmaxf(m, a);
      }
      #pragma unroll
      for (int off=32;off>0;off>>=1) m = fmaxf(m, __shfl_xor(m,off,64));
      float sum = 0.f;
      for (int j=r0+lane; j<r1; j+=64){
        int jj = eids[j]; int s = (jj<EE)? ei[jj] : jj-EE;
        float a = asv[s] + advn; a = (a>=0.f)? a : 0.2f*a;
        sum += expf(a - m);
      }
      #pragma unroll
      for (int off=32;off>0;off>>=1) sum += __shfl_xor(sum,off,64);
      float inv = 1.f / fmaxf(sum, 1e-16f);
      for (int j=r0+lane; j<r1; j+=64){
        int jj = eids[j]; int s = (jj<EE)? ei[jj] : jj-EE;
        float a = asv[s] + advn; a = (a>=0.f)? a : 0.2f*a;
        coef[j] = expf(a - m) * inv;
      }
    }
  }
  g.sync();

  // S3: aggregate + bias + relu  (2 nodes per block-iteration, 128 thr each)
  {
    int sub = threadIdx.x >> 7;        // 0/1
    int c   = threadIdx.x & 127;       // 128 threads * float4 = 512 ch
    for (int n = blockIdx.x*2 + sub; n < NN; n += gridDim.x*2){
      int r0 = rowptr[n], r1 = rowptr[n+1];
      float4 acc = {0.f,0.f,0.f,0.f};
      for (int j=r0;j<r1;j++){
        int jj = eids[j]; int s = (jj<EE)? ei[jj] : jj-EE;
        float cf = coef[j];
        const float4 hv = *(const float4*)&h[s*512 + c*4];
        acc.x += cf*hv.x; acc.y += cf*hv.y; acc.z += cf*hv.z; acc.w += cf*hv.w;
      }
      const float4 b = *(const float4*)&gat_b[c*4];
      float4 o;
      o.x = fmaxf(acc.x+b.x, 0.f); o.y = fmaxf(acc.y+b.y, 0.f);
      o.z = fmaxf(acc.z+b.z, 0.f); o.w = fmaxf(acc.w+b.w, 0.f);
      *(float4*)&gout[n*512 + c*4] = o;
    }
  }
}

// ============================ Kernel 4: edge MLP =============================
// S0: A = x@w1[:512], B = x@w1[512:]  (16-node tiles, 1 col/thread, no w redundancy)
// S1: per-edge MLP head
__global__ void __launch_bounds__(256) k_ABe(
    const float* __restrict__ x5, const float* __restrict__ w1,
    float* __restrict__ A, float* __restrict__ B,
    const int* __restrict__ ei, const float* __restrict__ b1,
    const float* __restrict__ w2, const float* __restrict__ b2,
    float* __restrict__ out){
  cg::grid_group g = cg::this_grid();
  __shared__ float sx[16*512];   // 32 KB

  for (int tile = blockIdx.x; tile < NN/16; tile += gridDim.x){
    __syncthreads();
    {
      const float4* src = (const float4*)(x5 + (size_t)tile*16*512);
      float4* dst = (float4*)sx;
      for (int q = threadIdx.x; q < 16*128; q += 256) dst[q] = src[q];
    }
    __syncthreads();
    int c    = threadIdx.x;
    int half = c >> 7;
    int j    = c & 127;
    const float* wcol = w1 + half*512*128 + j;
    float acc[16];
    #pragma unroll
    for (int k=0;k<16;k++) acc[k] = 0.f;
    for (int c4=0;c4<128;c4++){
      float w0 = wcol[(c4*4+0)*128];
      float w1v= wcol[(c4*4+1)*128];
      float w2v= wcol[(c4*4+2)*128];
      float w3v= wcol[(c4*4+3)*128];
      #pragma unroll
      for (int tt=0;tt<16;tt++){
        const float4 xv = *(const float4*)&sx[tt*512 + c4*4];
        acc[tt] += xv.x*w0 + xv.y*w1v + xv.z*w2v + xv.w*w3v;
      }
    }
    float* dst = half ? B : A;
    #pragma unroll
    for (int tt=0;tt<16;tt++) dst[(tile*16+tt)*128 + j] = acc[tt];
  }
  g.sync();

  // S1: edge head — one wave per edge
  {
    int gtid = blockIdx.x*256 + threadIdx.x;
    int wid = gtid >> 6, lane = gtid & 63, nw = (gridDim.x*256) >> 6;
    const float2 b1v = *(const float2*)&b1[lane*2];
    const float2 w2v = *(const float2*)&w2[lane*2];
    float bias2 = b2[0];
    for (int e = wid; e < EE; e += nw){
      int s = ei[e], d = ei[EE+e];
      const float2 av = *(const float2*)&A[s*128 + lane*2];
      const float2 bv = *(const float2*)&B[d*128 + lane*2];
      float h0 = fmaxf(av.x + bv.x + b1v.x, 0.f);
      float h1 = fmaxf(av.y + bv.y + b1v.y, 0.f);
      float acc = h0*w2v.x + h1*w2v.y;
      #pragma unroll
      for (int m=32;m>0;m>>=1) acc += __shfl_xor(acc,m,64);
      if (lane==0) out[e] = 1.f/(1.f + expf(-(acc + bias2)));
    }
  }
}

extern "C" void kernel_launch(void* const* d_in, const int* in_sizes, int n_in,
                              void* d_out, int out_size, void* d_ws, size_t ws_size,
                              hipStream_t stream){
  const float* basis0 = (const float*)d_in[0];
  const float* comp0  = (const float*)d_in[1];
  const float* root0  = (const float*)d_in[2];
  const float* rbias0 = (const float*)d_in[3];
  const float* basis1 = (const float*)d_in[4];
  const float* comp1  = (const float*)d_in[5];
  const float* root1  = (const float*)d_in[6];
  const float* rbias1 = (const float*)d_in[7];
  const float* basis2 = (const float*)d_in[8];
  const float* comp2  = (const float*)d_in[9];
  const float* root2  = (const float*)d_in[10];
  const float* rbias2 = (const float*)d_in[11];
  const float* basis3 = (const float*)d_in[12];
  const float* comp3  = (const float*)d_in[13];
  const float* root3  = (const float*)d_in[14];
  const float* rbias3 = (const float*)d_in[15];
  const float* gat_w = (const float*)d_in[16];
  const float* a_src = (const float*)d_in[17];
  const float* a_dst = (const float*)d_in[18];
  const float* gat_b = (const float*)d_in[19];
  const float* w1 = (const float*)d_in[20];
  const float* b1 = (const float*)d_in[21];
  const float* w2 = (const float*)d_in[22];
  const float* b2 = (const float*)d_in[23];
  const int* ei = (const int*)d_in[24];
  const int* et = (const int*)d_in[25];
  float* out = (float*)d_out;

  // workspace carve-up (deg+cnt adjacent -> single in-kernel zero pass)
  float* p = (float*)d_ws;
  int* deg    = (int*)p; p += NN;
  float* cnt  = p; p += 2*NN;
  int* rowptr = (int*)p; p += NN+4;   // padded for 16B alignment of later arrays
  int* cursor = (int*)p; p += NN;
  int* eids   = (int*)p; p += ELL;
  float* W0   = p; p += 2*NN*32;
  float* Wcat = p; p += 24576;
  float* xa   = p; p += NN*64;
  float* xb   = p; p += NN*64;
  float* H    = p; p += NN*192;
  float* h    = p; p += NN*512;
  float* asv  = p; p += NN;
  float* adv  = p; p += NN;
  float* coef = p; p += ELL + 2;      // keep next aligned
  float* gout = p; p += NN*512;
  float* A    = p; p += NN*128;
  float* B    = p; p += NN*128;

  // ---- 1. CSR + weight prep ----
  {
    void* args[] = {(void*)&ei,(void*)&et,(void*)&deg,(void*)&cnt,(void*)&rowptr,
                    (void*)&cursor,(void*)&eids,(void*)&basis0,(void*)&comp0,
                    (void*)&basis1,(void*)&comp1,(void*)&root1,
                    (void*)&basis2,(void*)&comp2,(void*)&root2,
                    (void*)&basis3,(void*)&comp3,(void*)&root3,
                    (void*)&W0,(void*)&Wcat};
    hipLaunchCooperativeKernel(k_csr, dim3(1024), dim3(256), args, 0, stream);
  }
  // ---- 2. RGCN stack ----
  {
    void* args[] = {(void*)&W0,(void*)&root0,(void*)&rbias0,(void*)&Wcat,
                    (void*)&rbias1,(void*)&rbias2,(void*)&rbias3,
                    (void*)&rowptr,(void*)&eids,(void*)&ei,(void*)&et,(void*)&cnt,
                    (void*)&xa,(void*)&xb,(void*)&H};
    hipLaunchCooperativeKernel(k_rgcn, dim3(1024), dim3(256), args, 0, stream);
  }
  // ---- 3. GAT (input xb) ----
  {
    const float* xin = xb;
    void* args[] = {(void*)&xin,(void*)&gat_w,(void*)&a_src,(void*)&a_dst,(void*)&gat_b,
                    (void*)&rowptr,(void*)&eids,(void*)&ei,
                    (void*)&h,(void*)&asv,(void*)&adv,(void*)&coef,(void*)&gout};
    hipLaunchCooperativeKernel(k_gat, dim3(1024), dim3(256), args, 0, stream);
  }
  // ---- 4. edge MLP ----
  {
    void* args[] = {(void*)&gout,(void*)&w1,(void*)&A,(void*)&B,
                    (void*)&ei,(void*)&b1,(void*)&w2,(void*)&b2,(void*)&out};
    hipLaunchCooperativeKernel(k_ABe, dim3(512), dim3(256), args, 0, stream);
  }
}

// Round 6
// 344.226 us; speedup vs baseline: 5.5410x; 5.5410x over previous
//
#include <hip/hip_runtime.h>
#include <math.h>

#define NN 6000
#define EE 100000
#define ELL (EE + NN)   // edges + self loops for GAT

// packed CSR entry: src (13b) | rel<<13 | self<<14
#define PK_SRC(p)  ((p) & 0x1FFF)
#define PK_REL(p)  (((p) >> 13) & 1)
#define PK_SELF(p) ((p) & 0x4000)

// fused degree + per-relation count (cnt immediately follows deg; one memset)
__global__ void k_degcnt(const int* __restrict__ ei, const int* __restrict__ et,
                         int* __restrict__ deg, float* __restrict__ cnt){
  int j = blockIdx.x*256 + threadIdx.x;
  if (j >= ELL) return;
  if (j < EE){
    int d = ei[EE+j]; int r = et[j];
    atomicAdd(&deg[d], 1);
    atomicAdd(&cnt[r*NN+d], 1.0f);
  } else {
    atomicAdd(&deg[j-EE], 1);
  }
}

// single-block exclusive scan over NN=6000 (256 threads x 24 elements)
__global__ void k_scan(const int* __restrict__ deg, int* __restrict__ rowptr,
                       int* __restrict__ cursor){
  __shared__ int ssum[256];
  const int PER = 24;
  int tid = threadIdx.x;
  int base = tid*PER;
  int local[PER];
  int s = 0;
  #pragma unroll
  for (int k=0;k<PER;k++){ int i = base+k; int v = (i<NN)?deg[i]:0; local[k]=s; s+=v; }
  ssum[tid] = s; __syncthreads();
  for (int off=1; off<256; off<<=1){
    int v = (tid>=off) ? ssum[tid-off] : 0;
    __syncthreads();
    ssum[tid] += v;
    __syncthreads();
  }
  int prefix = (tid==0) ? 0 : ssum[tid-1];
  #pragma unroll
  for (int k=0;k<PER;k++){
    int i = base+k;
    if (i<NN){ int v = prefix+local[k]; rowptr[i]=v; cursor[i]=v; }
  }
  if (tid==255) rowptr[NN] = ssum[255];
}

// fill packed-src CSR (one-hop: no eids->ei->et indirection later)
__global__ void k_fill(const int* __restrict__ ei, const int* __restrict__ et,
                       int* __restrict__ cursor, int* __restrict__ pks){
  int j = blockIdx.x*256 + threadIdx.x;
  if (j >= ELL) return;
  int d, pk;
  if (j < EE){ d = ei[EE+j]; pk = ei[j] | (et[j] << 13); }
  else       { d = j - EE;   pk = d | 0x4000; }
  int pos = atomicAdd(&cursor[d], 1);
  pks[pos] = pk;
}

// ---- merged weight prep: W0 [2,N,32] then Wcat (L1/L2/L3 packed, 24576) ----
__global__ void k_prep(const float* __restrict__ basis0, const float* __restrict__ comp0,
                       const float* __restrict__ b1,const float* __restrict__ c1,const float* __restrict__ r1,
                       const float* __restrict__ b2,const float* __restrict__ c2,const float* __restrict__ r2,
                       const float* __restrict__ b3,const float* __restrict__ c3,const float* __restrict__ r3,
                       float* __restrict__ W0, float* __restrict__ Wcat){
  int t0 = blockIdx.x*256 + threadIdx.x;
  if (t0 < 2*NN*32){
    int r = t0 / (NN*32);
    int no = t0 - r*(NN*32);
    float acc = 0.f;
    #pragma unroll
    for (int b=0;b<4;b++) acc += comp0[r*4+b] * basis0[b*(NN*32)+no];
    W0[t0] = acc;
    return;
  }
  int tw = t0 - 2*NN*32;
  if (tw >= 24576) return;
  const float *bb,*cc,*rr; int I,O; int t = tw;
  if (tw < 6144)        { bb=b1;cc=c1;rr=r1;I=32;O=64; }
  else if (tw < 18432)  { bb=b2;cc=c2;rr=r2;I=64;O=64; t -= 6144; }
  else                  { bb=b3;cc=c3;rr=r3;I=64;O=32; t -= 18432; }
  int C = 3*O;
  int i = t / C; int col = t - i*C;
  float v;
  if (col < O) v = rr[i*O + col];
  else {
    int r = (col - O) / O; int o = col - O - r*O;
    v = 0.f;
    #pragma unroll
    for (int b=0;b<4;b++) v += cc[r*4+b]*bb[(b*I+i)*O + o];
  }
  Wcat[tw] = v;
}

// fused layer-0 aggregation + combine + tanh (x = I)
__global__ void k_ragg0(const float* __restrict__ W0, const float* __restrict__ root,
                        const float* __restrict__ rbias,
                        const int* __restrict__ rowptr, const int* __restrict__ pks,
                        const float* __restrict__ cnt, float* __restrict__ xout){
  int n = blockIdx.x*8 + (threadIdx.x >> 5);
  int o = threadIdx.x & 31;
  if (n >= NN) return;
  int r0 = rowptr[n], r1 = rowptr[n+1];
  float a0 = 0.f, a1 = 0.f;
  for (int j=r0;j<r1;j++){
    int p = pks[j];
    if (PK_SELF(p)) continue;
    float v = W0[(PK_REL(p)*NN + PK_SRC(p))*32 + o];
    if (PK_REL(p)==0) a0 += v; else a1 += v;
  }
  float v = root[n*32+o] + rbias[o]
          + a0/fmaxf(cnt[n],1.f) + a1/fmaxf(cnt[NN+n],1.f);
  xout[n*32+o] = tanhf(v);
}

// H = x @ Wcat : [N, 3O] — 8 nodes/block, 192 threads, Wcat read once per block
template<int I>
__global__ void __launch_bounds__(192) k_nodemm(const float* __restrict__ x,
                                                const float* __restrict__ Wc,
                                                float* __restrict__ H){
  __shared__ float sx[8*I];
  int n0 = blockIdx.x*8;
  for (int c = threadIdx.x; c < 8*I; c += 192) sx[c] = x[n0*I + c];
  __syncthreads();
  int c = threadIdx.x;      // 0..191
  float acc[8] = {0,0,0,0,0,0,0,0};
  for (int i=0;i<I;i++){
    float w = Wc[i*192 + c];
    #pragma unroll
    for (int tt=0;tt<8;tt++) acc[tt] += sx[tt*I + i] * w;
  }
  #pragma unroll
  for (int tt=0;tt<8;tt++) H[(n0+tt)*192 + c] = acc[tt];
}

// fused RGCN agg + mean + root + tanh for layers 1..3
template<int O>
__global__ void k_ragg(const float* __restrict__ H, const float* __restrict__ rbias,
                       const int* __restrict__ rowptr, const int* __restrict__ pks,
                       const float* __restrict__ cnt, float* __restrict__ xout){
  constexpr int NPB = 256/O;
  int n = blockIdx.x*NPB + threadIdx.x/O;
  int o = threadIdx.x % O;
  if (n >= NN) return;
  int r0 = rowptr[n], r1 = rowptr[n+1];
  float a0 = 0.f, a1 = 0.f;
  for (int j=r0;j<r1;j++){
    int p = pks[j];
    if (PK_SELF(p)) continue;
    int rel = PK_REL(p);
    float v = H[PK_SRC(p)*3*O + O + rel*O + o];
    if (rel==0) a0 += v; else a1 += v;
  }
  float v = H[n*3*O + o] + rbias[o]
          + a0/fmaxf(cnt[n],1.f) + a1/fmaxf(cnt[NN+n],1.f);
  xout[n*O+o] = tanhf(v);
}

// ---- GAT: h = x@gw (8 nodes/block) fused with per-node scores ----
__global__ void k_gat(const float* __restrict__ x, const float* __restrict__ gw,
                      const float* __restrict__ as_, const float* __restrict__ ad_,
                      float* __restrict__ h, float* __restrict__ asv, float* __restrict__ adv){
  int n0 = blockIdx.x*8;
  int t = threadIdx.x;  // 128 threads
  __shared__ float sx[8*32];
  __shared__ float red[2][16];
  for (int c=t; c<8*32; c+=128) sx[c] = x[n0*32 + c];
  __syncthreads();
  float4 acc[8];
  #pragma unroll
  for (int k=0;k<8;k++) acc[k] = {0,0,0,0};
  for (int i=0;i<32;i++){
    const float4 g = *(const float4*)&gw[i*512 + t*4];
    #pragma unroll
    for (int k=0;k<8;k++){
      float xv = sx[k*32+i];
      acc[k].x += xv*g.x; acc[k].y += xv*g.y; acc[k].z += xv*g.z; acc[k].w += xv*g.w;
    }
  }
  const float4 a4 = *(const float4*)&as_[t*4];
  const float4 d4 = *(const float4*)&ad_[t*4];
  float sa[8], sd[8];
  #pragma unroll
  for (int k=0;k<8;k++){
    *(float4*)&h[(n0+k)*512 + t*4] = acc[k];
    sa[k] = acc[k].x*a4.x + acc[k].y*a4.y + acc[k].z*a4.z + acc[k].w*a4.w;
    sd[k] = acc[k].x*d4.x + acc[k].y*d4.y + acc[k].z*d4.z + acc[k].w*d4.w;
  }
  #pragma unroll
  for (int m=32;m>0;m>>=1){
    #pragma unroll
    for (int k=0;k<8;k++){ sa[k] += __shfl_xor(sa[k],m,64); sd[k] += __shfl_xor(sd[k],m,64); }
  }
  int wv = t>>6;
  if ((t&63)==0){
    #pragma unroll
    for (int k=0;k<8;k++){ red[wv][k]=sa[k]; red[wv][8+k]=sd[k]; }
  }
  __syncthreads();
  if (t<8)              asv[n0+t]   = red[0][t]+red[1][t];
  else if (t<16)        adv[n0+t-8] = red[0][t]+red[1][t];
}

// fused per-node softmax over incident edges; coef stored by CSR slot
__global__ void k_gat_soft(const int* __restrict__ rowptr, const int* __restrict__ pks,
                           const float* __restrict__ asv, const float* __restrict__ adv,
                           float* __restrict__ coef){
  int n = blockIdx.x*4 + (threadIdx.x >> 6);
  int lane = threadIdx.x & 63;
  if (n >= NN) return;
  int r0 = rowptr[n], r1 = rowptr[n+1];
  float advn = adv[n];
  float m = -1e30f;
  for (int j=r0+lane; j<r1; j+=64){
    float a = asv[PK_SRC(pks[j])] + advn; a = (a>=0.f)? a : 0.2f*a;
    m = fmaxf(m, a);
  }
  #pragma unroll
  for (int off=32;off>0;off>>=1) m = fmaxf(m, __shfl_xor(m,off,64));
  float sum = 0.f;
  for (int j=r0+lane; j<r1; j+=64){
    float a = asv[PK_SRC(pks[j])] + advn; a = (a>=0.f)? a : 0.2f*a;
    sum += expf(a - m);
  }
  #pragma unroll
  for (int off=32;off>0;off>>=1) sum += __shfl_xor(sum,off,64);
  float inv = 1.f / fmaxf(sum, 1e-16f);
  for (int j=r0+lane; j<r1; j+=64){
    float a = asv[PK_SRC(pks[j])] + advn; a = (a>=0.f)? a : 0.2f*a;
    coef[j] = expf(a - m) * inv;
  }
}

// per-node gather aggregation + bias + relu (2-edge unroll for MLP)
__global__ void k_gat_agg(const int* __restrict__ rowptr, const int* __restrict__ pks,
                          const float* __restrict__ coef, const float* __restrict__ h,
                          const float* __restrict__ bias, float* __restrict__ gout){
  int n = blockIdx.x;
  int c = threadIdx.x;             // 128 threads * float4 = 512 channels
  int r0 = rowptr[n], r1 = rowptr[n+1];
  float4 acc = {0.f,0.f,0.f,0.f};
  int j = r0;
  for (; j+2<=r1; j+=2){
    int p0 = pks[j], p1 = pks[j+1];
    float c0 = coef[j], c1 = coef[j+1];
    const float4 h0 = *(const float4*)&h[PK_SRC(p0)*512 + c*4];
    const float4 h1 = *(const float4*)&h[PK_SRC(p1)*512 + c*4];
    acc.x += c0*h0.x + c1*h1.x; acc.y += c0*h0.y + c1*h1.y;
    acc.z += c0*h0.z + c1*h1.z; acc.w += c0*h0.w + c1*h1.w;
  }
  if (j < r1){
    int p0 = pks[j]; float c0 = coef[j];
    const float4 h0 = *(const float4*)&h[PK_SRC(p0)*512 + c*4];
    acc.x += c0*h0.x; acc.y += c0*h0.y; acc.z += c0*h0.z; acc.w += c0*h0.w;
  }
  const float4 b = *(const float4*)&bias[c*4];
  float4 o;
  o.x = fmaxf(acc.x+b.x, 0.f); o.y = fmaxf(acc.y+b.y, 0.f);
  o.z = fmaxf(acc.z+b.z, 0.f); o.w = fmaxf(acc.w+b.w, 0.f);
  *(float4*)&gout[n*512 + c*4] = o;
}

// ---- edge MLP precompute: A = x@w1[:512], B = x@w1[512:] ----
// 375 blocks x 16 nodes x 256 cols; thread = 8 nodes x 2 cols; x via LDS broadcast
__global__ void __launch_bounds__(256) k_AB(const float* __restrict__ x5,
                                            const float* __restrict__ w1,
                                            float* __restrict__ A, float* __restrict__ B){
  __shared__ float sx[16*512];   // 32 KB
  int n0 = blockIdx.x*16;
  {
    const float4* src = (const float4*)(x5 + (size_t)n0*512);
    float4* dst = (float4*)sx;
    for (int q = threadIdx.x; q < 16*128; q += 256) dst[q] = src[q];
  }
  __syncthreads();
  int q0 = (threadIdx.x & 127) * 2;        // output col pair 0..254
  int ng = threadIdx.x >> 7;               // node group: 8 nodes each
  const float* wbase = (q0 < 128) ? (w1 + q0) : (w1 + 512*128 + (q0 - 128));
  float acc[16];
  #pragma unroll
  for (int k=0;k<16;k++) acc[k] = 0.f;
  for (int k4=0;k4<128;k4++){
    const float2 w0 = *(const float2*)(wbase + (k4*4+0)*128);
    const float2 w1v= *(const float2*)(wbase + (k4*4+1)*128);
    const float2 w2v= *(const float2*)(wbase + (k4*4+2)*128);
    const float2 w3v= *(const float2*)(wbase + (k4*4+3)*128);
    #pragma unroll
    for (int tt=0;tt<8;tt++){
      const float4 xv = *(const float4*)&sx[(ng*8+tt)*512 + k4*4];
      acc[tt*2]   += xv.x*w0.x + xv.y*w1v.x + xv.z*w2v.x + xv.w*w3v.x;
      acc[tt*2+1] += xv.x*w0.y + xv.y*w1v.y + xv.z*w2v.y + xv.w*w3v.y;
    }
  }
  float* dst = (q0 < 128) ? A : B;
  int col = q0 & 127;
  #pragma unroll
  for (int tt=0;tt<8;tt++){
    float2 o = {acc[tt*2], acc[tt*2+1]};
    *(float2*)&dst[(n0 + ng*8 + tt)*128 + col] = o;
  }
}

__global__ void k_edge(const int* __restrict__ ei, const float* __restrict__ A,
                       const float* __restrict__ B, const float* __restrict__ b1,
                       const float* __restrict__ w2, const float* __restrict__ b2,
                       float* __restrict__ out){
  int e = blockIdx.x*4 + (threadIdx.x >> 6);
  int lane = threadIdx.x & 63;
  if (e >= EE) return;
  int s = ei[e], d = ei[EE+e];
  const float2 av = *(const float2*)&A[s*128 + lane*2];
  const float2 bv = *(const float2*)&B[d*128 + lane*2];
  const float2 b1v = *(const float2*)&b1[lane*2];
  const float2 w2v = *(const float2*)&w2[lane*2];
  float h0 = fmaxf(av.x + bv.x + b1v.x, 0.f);
  float h1 = fmaxf(av.y + bv.y + b1v.y, 0.f);
  float acc = h0*w2v.x + h1*w2v.y;
  #pragma unroll
  for (int m=32;m>0;m>>=1) acc += __shfl_xor(acc,m,64);
  if (lane==0) out[e] = 1.f/(1.f + expf(-(acc + b2[0])));
}

extern "C" void kernel_launch(void* const* d_in, const int* in_sizes, int n_in,
                              void* d_out, int out_size, void* d_ws, size_t ws_size,
                              hipStream_t stream){
  const float* basis0 = (const float*)d_in[0];
  const float* comp0  = (const float*)d_in[1];
  const float* root0  = (const float*)d_in[2];
  const float* rbias0 = (const float*)d_in[3];
  const float* basis1 = (const float*)d_in[4];
  const float* comp1  = (const float*)d_in[5];
  const float* root1  = (const float*)d_in[6];
  const float* rbias1 = (const float*)d_in[7];
  const float* basis2 = (const float*)d_in[8];
  const float* comp2  = (const float*)d_in[9];
  const float* root2  = (const float*)d_in[10];
  const float* rbias2 = (const float*)d_in[11];
  const float* basis3 = (const float*)d_in[12];
  const float* comp3  = (const float*)d_in[13];
  const float* root3  = (const float*)d_in[14];
  const float* rbias3 = (const float*)d_in[15];
  const float* gat_w = (const float*)d_in[16];
  const float* a_src = (const float*)d_in[17];
  const float* a_dst = (const float*)d_in[18];
  const float* gat_b = (const float*)d_in[19];
  const float* w1 = (const float*)d_in[20];
  const float* b1 = (const float*)d_in[21];
  const float* w2 = (const float*)d_in[22];
  const float* b2 = (const float*)d_in[23];
  const int* ei = (const int*)d_in[24];
  const int* et = (const int*)d_in[25];
  float* out = (float*)d_out;

  // workspace carve-up (deg+cnt adjacent: one memset)
  float* p = (float*)d_ws;
  int* deg    = (int*)p; p += NN;
  float* cnt  = p; p += 2*NN;
  int* rowptr = (int*)p; p += NN+4;
  int* cursor = (int*)p; p += NN;
  int* pks    = (int*)p; p += ELL + 2;
  float* W0   = p; p += 2*NN*32;
  float* Wcat = p; p += 24576;
  float* xa   = p; p += NN*64;
  float* xb   = p; p += NN*64;
  float* H    = p; p += NN*192;
  float* h    = p; p += NN*512;
  float* asv  = p; p += NN;
  float* adv  = p; p += NN;
  float* coef = p; p += ELL + 2;
  float* gout = p; p += NN*512;
  float* A    = p; p += NN*128;
  float* B    = p; p += NN*128;

  auto grid = [](long long n){ return dim3((unsigned)((n + 255)/256)); };

  // ---- weight prep ----
  k_prep<<<grid(2LL*NN*32 + 24576),256,0,stream>>>(basis0, comp0,
        basis1,comp1,root1, basis2,comp2,root2, basis3,comp3,root3, W0, Wcat);

  // ---- CSR build ----
  hipMemsetAsync(deg, 0, (size_t)3*NN*sizeof(int), stream);  // deg + cnt
  k_degcnt<<<grid(ELL),256,0,stream>>>(ei, et, deg, cnt);
  k_scan<<<1,256,0,stream>>>(deg, rowptr, cursor);
  k_fill<<<grid(ELL),256,0,stream>>>(ei, et, cursor, pks);

  // ---- RGCN layer 0 (x = I) ----
  k_ragg0<<<dim3((NN+7)/8),256,0,stream>>>(W0, root0, rbias0, rowptr, pks, cnt, xa);

  // ---- RGCN layers 1..3 ----
  k_nodemm<32><<<dim3(750),192,0,stream>>>(xa, Wcat,         H);
  k_ragg<64><<<dim3((NN+3)/4),256,0,stream>>>(H, rbias1, rowptr, pks, cnt, xb);
  k_nodemm<64><<<dim3(750),192,0,stream>>>(xb, Wcat + 6144,  H);
  k_ragg<64><<<dim3((NN+3)/4),256,0,stream>>>(H, rbias2, rowptr, pks, cnt, xa);
  k_nodemm<64><<<dim3(750),192,0,stream>>>(xa, Wcat + 18432, H);
  k_ragg<32><<<dim3((NN+7)/8),256,0,stream>>>(H, rbias3, rowptr, pks, cnt, xb);
  // final RGCN output (N x 32) in xb

  // ---- GAT ----
  k_gat<<<dim3(NN/8),128,0,stream>>>(xb, gat_w, a_src, a_dst, h, asv, adv);
  k_gat_soft<<<dim3((NN+3)/4),256,0,stream>>>(rowptr, pks, asv, adv, coef);
  k_gat_agg<<<dim3(NN),128,0,stream>>>(rowptr, pks, coef, h, gat_b, gout);

  // ---- edge MLP ----
  k_AB<<<dim3(375),256,0,stream>>>(gout, w1, A, B);
  k_edge<<<dim3((EE+3)/4),256,0,stream>>>(ei, A, B, b1, w2, b2, out);
}

// Round 7
// 340.322 us; speedup vs baseline: 5.6046x; 1.0115x over previous
//
#include <hip/hip_runtime.h>
#include <math.h>

#define NN 6000
#define EE 100000
#define ELL (EE + NN)   // edges + self loops for GAT

// packed CSR entry: src (13b) | rel<<13 | self<<14
#define PK_SRC(p)  ((p) & 0x1FFF)
#define PK_REL(p)  (((p) >> 13) & 1)
#define PK_SELF(p) ((p) & 0x4000)

// ---- fused: degree + per-relation count + weight prep (independent work) ----
__global__ void k_pdc(const int* __restrict__ ei, const int* __restrict__ et,
                      int* __restrict__ deg, float* __restrict__ cnt,
                      const float* __restrict__ basis0, const float* __restrict__ comp0,
                      const float* __restrict__ b1,const float* __restrict__ c1,const float* __restrict__ r1,
                      const float* __restrict__ b2,const float* __restrict__ c2,const float* __restrict__ r2,
                      const float* __restrict__ b3,const float* __restrict__ c3,const float* __restrict__ r3,
                      float* __restrict__ W0, float* __restrict__ Wcat){
  int t0 = blockIdx.x*256 + threadIdx.x;
  // part 1: degree/count
  if (t0 < ELL){
    if (t0 < EE){
      int d = ei[EE+t0]; int r = et[t0];
      atomicAdd(&deg[d], 1);
      atomicAdd(&cnt[r*NN+d], 1.0f);
    } else {
      atomicAdd(&deg[t0-EE], 1);
    }
  }
  // part 2: weight prep
  if (t0 < 2*NN*32){
    int r = t0 / (NN*32);
    int no = t0 - r*(NN*32);
    float acc = 0.f;
    #pragma unroll
    for (int b=0;b<4;b++) acc += comp0[r*4+b] * basis0[b*(NN*32)+no];
    W0[t0] = acc;
    return;
  }
  int tw = t0 - 2*NN*32;
  if (tw >= 24576) return;
  const float *bb,*cc,*rr; int I,O; int t = tw;
  if (tw < 6144)        { bb=b1;cc=c1;rr=r1;I=32;O=64; }
  else if (tw < 18432)  { bb=b2;cc=c2;rr=r2;I=64;O=64; t -= 6144; }
  else                  { bb=b3;cc=c3;rr=r3;I=64;O=32; t -= 18432; }
  int C = 3*O;
  int i = t / C; int col = t - i*C;
  float v;
  if (col < O) v = rr[i*O + col];
  else {
    int r = (col - O) / O; int o = col - O - r*O;
    v = 0.f;
    #pragma unroll
    for (int b=0;b<4;b++) v += cc[r*4+b]*bb[(b*I+i)*O + o];
  }
  Wcat[tw] = v;
}

// single-block exclusive scan over NN=6000 (256 threads x 24 elements)
__global__ void k_scan(const int* __restrict__ deg, int* __restrict__ rowptr,
                       int* __restrict__ cursor){
  __shared__ int ssum[256];
  const int PER = 24;
  int tid = threadIdx.x;
  int base = tid*PER;
  int local[PER];
  int s = 0;
  #pragma unroll
  for (int k=0;k<PER;k++){ int i = base+k; int v = (i<NN)?deg[i]:0; local[k]=s; s+=v; }
  ssum[tid] = s; __syncthreads();
  for (int off=1; off<256; off<<=1){
    int v = (tid>=off) ? ssum[tid-off] : 0;
    __syncthreads();
    ssum[tid] += v;
    __syncthreads();
  }
  int prefix = (tid==0) ? 0 : ssum[tid-1];
  #pragma unroll
  for (int k=0;k<PER;k++){
    int i = base+k;
    if (i<NN){ int v = prefix+local[k]; rowptr[i]=v; cursor[i]=v; }
  }
  if (tid==255) rowptr[NN] = ssum[255];
}

// fill packed-src CSR
__global__ void k_fill(const int* __restrict__ ei, const int* __restrict__ et,
                       int* __restrict__ cursor, int* __restrict__ pks){
  int j = blockIdx.x*256 + threadIdx.x;
  if (j >= ELL) return;
  int d, pk;
  if (j < EE){ d = ei[EE+j]; pk = ei[j] | (et[j] << 13); }
  else       { d = j - EE;   pk = d | 0x4000; }
  int pos = atomicAdd(&cursor[d], 1);
  pks[pos] = pk;
}

// fused layer-0 aggregation + combine + tanh (x = I)
__global__ void k_ragg0(const float* __restrict__ W0, const float* __restrict__ root,
                        const float* __restrict__ rbias,
                        const int* __restrict__ rowptr, const int* __restrict__ pks,
                        const float* __restrict__ cnt, float* __restrict__ xout){
  int n = blockIdx.x*8 + (threadIdx.x >> 5);
  int o = threadIdx.x & 31;
  if (n >= NN) return;
  int r0 = rowptr[n], r1 = rowptr[n+1];
  float a0 = 0.f, a1 = 0.f;
  for (int j=r0;j<r1;j++){
    int p = pks[j];
    if (PK_SELF(p)) continue;
    float v = W0[(PK_REL(p)*NN + PK_SRC(p))*32 + o];
    if (PK_REL(p)==0) a0 += v; else a1 += v;
  }
  float v = root[n*32+o] + rbias[o]
          + a0/fmaxf(cnt[n],1.f) + a1/fmaxf(cnt[NN+n],1.f);
  xout[n*32+o] = tanhf(v);
}

// H = x @ Wcat : [N, 3O] — 8 nodes/block, 192 threads
template<int I>
__global__ void __launch_bounds__(192) k_nodemm(const float* __restrict__ x,
                                                const float* __restrict__ Wc,
                                                float* __restrict__ H){
  __shared__ float sx[8*I];
  int n0 = blockIdx.x*8;
  for (int c = threadIdx.x; c < 8*I; c += 192) sx[c] = x[n0*I + c];
  __syncthreads();
  int c = threadIdx.x;      // 0..191
  float acc[8] = {0,0,0,0,0,0,0,0};
  for (int i=0;i<I;i++){
    float w = Wc[i*192 + c];
    #pragma unroll
    for (int tt=0;tt<8;tt++) acc[tt] += sx[tt*I + i] * w;
  }
  #pragma unroll
  for (int tt=0;tt<8;tt++) H[(n0+tt)*192 + c] = acc[tt];
}

// fused RGCN agg + mean + root + tanh for layers 1..3
template<int O>
__global__ void k_ragg(const float* __restrict__ H, const float* __restrict__ rbias,
                       const int* __restrict__ rowptr, const int* __restrict__ pks,
                       const float* __restrict__ cnt, float* __restrict__ xout){
  constexpr int NPB = 256/O;
  int n = blockIdx.x*NPB + threadIdx.x/O;
  int o = threadIdx.x % O;
  if (n >= NN) return;
  int r0 = rowptr[n], r1 = rowptr[n+1];
  float a0 = 0.f, a1 = 0.f;
  for (int j=r0;j<r1;j++){
    int p = pks[j];
    if (PK_SELF(p)) continue;
    int rel = PK_REL(p);
    float v = H[PK_SRC(p)*3*O + O + rel*O + o];
    if (rel==0) a0 += v; else a1 += v;
  }
  float v = H[n*3*O + o] + rbias[o]
          + a0/fmaxf(cnt[n],1.f) + a1/fmaxf(cnt[NN+n],1.f);
  xout[n*O+o] = tanhf(v);
}

// ---- GAT: h = x@gw (8 nodes/block) fused with per-node scores ----
__global__ void k_gat(const float* __restrict__ x, const float* __restrict__ gw,
                      const float* __restrict__ as_, const float* __restrict__ ad_,
                      float* __restrict__ h, float* __restrict__ asv, float* __restrict__ adv){
  int n0 = blockIdx.x*8;
  int t = threadIdx.x;  // 128 threads
  __shared__ float sx[8*32];
  __shared__ float red[2][16];
  for (int c=t; c<8*32; c+=128) sx[c] = x[n0*32 + c];
  __syncthreads();
  float4 acc[8];
  #pragma unroll
  for (int k=0;k<8;k++) acc[k] = {0,0,0,0};
  for (int i=0;i<32;i++){
    const float4 g = *(const float4*)&gw[i*512 + t*4];
    #pragma unroll
    for (int k=0;k<8;k++){
      float xv = sx[k*32+i];
      acc[k].x += xv*g.x; acc[k].y += xv*g.y; acc[k].z += xv*g.z; acc[k].w += xv*g.w;
    }
  }
  const float4 a4 = *(const float4*)&as_[t*4];
  const float4 d4 = *(const float4*)&ad_[t*4];
  float sa[8], sd[8];
  #pragma unroll
  for (int k=0;k<8;k++){
    *(float4*)&h[(n0+k)*512 + t*4] = acc[k];
    sa[k] = acc[k].x*a4.x + acc[k].y*a4.y + acc[k].z*a4.z + acc[k].w*a4.w;
    sd[k] = acc[k].x*d4.x + acc[k].y*d4.y + acc[k].z*d4.z + acc[k].w*d4.w;
  }
  #pragma unroll
  for (int m=32;m>0;m>>=1){
    #pragma unroll
    for (int k=0;k<8;k++){ sa[k] += __shfl_xor(sa[k],m,64); sd[k] += __shfl_xor(sd[k],m,64); }
  }
  int wv = t>>6;
  if ((t&63)==0){
    #pragma unroll
    for (int k=0;k<8;k++){ red[wv][k]=sa[k]; red[wv][8+k]=sd[k]; }
  }
  __syncthreads();
  if (t<8)              asv[n0+t]   = red[0][t]+red[1][t];
  else if (t<16)        adv[n0+t-8] = red[0][t]+red[1][t];
}

// per-node softmax, 16 lanes per node (deg ~17.7), ex cached in coef
__global__ void k_gat_soft(const int* __restrict__ rowptr, const int* __restrict__ pks,
                           const float* __restrict__ asv, const float* __restrict__ adv,
                           float* __restrict__ coef){
  int n = blockIdx.x*16 + (threadIdx.x >> 4);
  int lane = threadIdx.x & 15;
  if (n >= NN) return;
  int r0 = rowptr[n], r1 = rowptr[n+1];
  float advn = adv[n];
  float m = -1e30f;
  for (int j=r0+lane; j<r1; j+=16){
    float a = asv[PK_SRC(pks[j])] + advn; a = (a>=0.f)? a : 0.2f*a;
    m = fmaxf(m, a);
  }
  #pragma unroll
  for (int off=8;off>0;off>>=1) m = fmaxf(m, __shfl_xor(m,off,64));
  float sum = 0.f;
  for (int j=r0+lane; j<r1; j+=16){
    float a = asv[PK_SRC(pks[j])] + advn; a = (a>=0.f)? a : 0.2f*a;
    float ex = expf(a - m);
    coef[j] = ex;
    sum += ex;
  }
  #pragma unroll
  for (int off=8;off>0;off>>=1) sum += __shfl_xor(sum,off,64);
  float inv = 1.f / fmaxf(sum, 1e-16f);
  for (int j=r0+lane; j<r1; j+=16) coef[j] *= inv;
}

// per-node gather aggregation + bias + relu
__global__ void k_gat_agg(const int* __restrict__ rowptr, const int* __restrict__ pks,
                          const float* __restrict__ coef, const float* __restrict__ h,
                          const float* __restrict__ bias, float* __restrict__ gout){
  int n = blockIdx.x;
  int c = threadIdx.x;             // 128 threads * float4 = 512 channels
  int r0 = rowptr[n], r1 = rowptr[n+1];
  float4 acc = {0.f,0.f,0.f,0.f};
  int j = r0;
  for (; j+2<=r1; j+=2){
    int p0 = pks[j], p1 = pks[j+1];
    float c0 = coef[j], c1 = coef[j+1];
    const float4 h0 = *(const float4*)&h[PK_SRC(p0)*512 + c*4];
    const float4 h1 = *(const float4*)&h[PK_SRC(p1)*512 + c*4];
    acc.x += c0*h0.x + c1*h1.x; acc.y += c0*h0.y + c1*h1.y;
    acc.z += c0*h0.z + c1*h1.z; acc.w += c0*h0.w + c1*h1.w;
  }
  if (j < r1){
    int p0 = pks[j]; float c0 = coef[j];
    const float4 h0 = *(const float4*)&h[PK_SRC(p0)*512 + c*4];
    acc.x += c0*h0.x; acc.y += c0*h0.y; acc.z += c0*h0.z; acc.w += c0*h0.w;
  }
  const float4 b = *(const float4*)&bias[c*4];
  float4 o;
  o.x = fmaxf(acc.x+b.x, 0.f); o.y = fmaxf(acc.y+b.y, 0.f);
  o.z = fmaxf(acc.z+b.z, 0.f); o.w = fmaxf(acc.w+b.w, 0.f);
  *(float4*)&gout[n*512 + c*4] = o;
}

// ---- edge MLP precompute, split-K=2: P[kh][n][0:128]=A part, [128:256]=B part ----
// 1500 blocks = 750 node-tiles (8 nodes) x 2 k-halves; 1 col/thread (no w redundancy)
__global__ void __launch_bounds__(256) k_AB(const float* __restrict__ x5,
                                            const float* __restrict__ w1,
                                            float* __restrict__ P){
  __shared__ float sx[8*256];   // 8 KB: 8 nodes x 256 k (this half)
  int b = blockIdx.x;
  int tile = b >> 1, kh = b & 1;
  int n0 = tile*8;
  {
    float4* dst = (float4*)sx;
    for (int q = threadIdx.x; q < 8*64; q += 256){
      int node = q >> 6, kq = q & 63;
      dst[q] = *(const float4*)&x5[(n0+node)*512 + kh*256 + kq*4];
    }
  }
  __syncthreads();
  int col = threadIdx.x;   // 0..255: <128 -> A col, >=128 -> B col
  const float* wcol = ((col < 128) ? (w1 + col) : (w1 + 512*128 + (col-128)))
                      + (size_t)(kh*256)*128;
  float acc[8] = {0,0,0,0,0,0,0,0};
  for (int k4=0;k4<64;k4++){
    float w0 = wcol[(k4*4+0)*128];
    float w1v= wcol[(k4*4+1)*128];
    float w2v= wcol[(k4*4+2)*128];
    float w3v= wcol[(k4*4+3)*128];
    #pragma unroll
    for (int tt=0;tt<8;tt++){
      const float4 xv = *(const float4*)&sx[tt*256 + k4*4];
      acc[tt] += xv.x*w0 + xv.y*w1v + xv.z*w2v + xv.w*w3v;
    }
  }
  float* dst = P + (size_t)kh*NN*256;
  #pragma unroll
  for (int tt=0;tt<8;tt++) dst[(n0+tt)*256 + col] = acc[tt];
}

__global__ void k_edge(const int* __restrict__ ei, const float* __restrict__ P,
                       const float* __restrict__ b1,
                       const float* __restrict__ w2, const float* __restrict__ b2,
                       float* __restrict__ out){
  int e = blockIdx.x*4 + (threadIdx.x >> 6);
  int lane = threadIdx.x & 63;
  if (e >= EE) return;
  int s = ei[e], d = ei[EE+e];
  const float2 a0 = *(const float2*)&P[s*256 + lane*2];
  const float2 a1 = *(const float2*)&P[(size_t)NN*256 + s*256 + lane*2];
  const float2 c0 = *(const float2*)&P[d*256 + 128 + lane*2];
  const float2 c1 = *(const float2*)&P[(size_t)NN*256 + d*256 + 128 + lane*2];
  const float2 b1v = *(const float2*)&b1[lane*2];
  const float2 w2v = *(const float2*)&w2[lane*2];
  float h0 = fmaxf(a0.x + a1.x + c0.x + c1.x + b1v.x, 0.f);
  float h1 = fmaxf(a0.y + a1.y + c0.y + c1.y + b1v.y, 0.f);
  float acc = h0*w2v.x + h1*w2v.y;
  #pragma unroll
  for (int m=32;m>0;m>>=1) acc += __shfl_xor(acc,m,64);
  if (lane==0) out[e] = 1.f/(1.f + expf(-(acc + b2[0])));
}

extern "C" void kernel_launch(void* const* d_in, const int* in_sizes, int n_in,
                              void* d_out, int out_size, void* d_ws, size_t ws_size,
                              hipStream_t stream){
  const float* basis0 = (const float*)d_in[0];
  const float* comp0  = (const float*)d_in[1];
  const float* root0  = (const float*)d_in[2];
  const float* rbias0 = (const float*)d_in[3];
  const float* basis1 = (const float*)d_in[4];
  const float* comp1  = (const float*)d_in[5];
  const float* root1  = (const float*)d_in[6];
  const float* rbias1 = (const float*)d_in[7];
  const float* basis2 = (const float*)d_in[8];
  const float* comp2  = (const float*)d_in[9];
  const float* root2  = (const float*)d_in[10];
  const float* rbias2 = (const float*)d_in[11];
  const float* basis3 = (const float*)d_in[12];
  const float* comp3  = (const float*)d_in[13];
  const float* root3  = (const float*)d_in[14];
  const float* rbias3 = (const float*)d_in[15];
  const float* gat_w = (const float*)d_in[16];
  const float* a_src = (const float*)d_in[17];
  const float* a_dst = (const float*)d_in[18];
  const float* gat_b = (const float*)d_in[19];
  const float* w1 = (const float*)d_in[20];
  const float* b1 = (const float*)d_in[21];
  const float* w2 = (const float*)d_in[22];
  const float* b2 = (const float*)d_in[23];
  const int* ei = (const int*)d_in[24];
  const int* et = (const int*)d_in[25];
  float* out = (float*)d_out;

  // workspace carve-up (deg+cnt adjacent: one memset)
  float* p = (float*)d_ws;
  int* deg    = (int*)p; p += NN;
  float* cnt  = p; p += 2*NN;
  int* rowptr = (int*)p; p += NN+4;
  int* cursor = (int*)p; p += NN;
  int* pks    = (int*)p; p += ELL + 2;
  float* W0   = p; p += 2*NN*32;
  float* Wcat = p; p += 24576;
  float* xa   = p; p += NN*64;
  float* xb   = p; p += NN*64;
  float* H    = p; p += NN*192;
  float* h    = p; p += NN*512;
  float* asv  = p; p += NN;
  float* adv  = p; p += NN;
  float* coef = p; p += ELL + 2;
  float* gout = p; p += NN*512;
  float* P    = p; p += 2*NN*256;

  auto grid = [](long long n){ return dim3((unsigned)((n + 255)/256)); };

  // ---- CSR build + weight prep (fused) ----
  hipMemsetAsync(deg, 0, (size_t)3*NN*sizeof(int), stream);  // deg + cnt
  k_pdc<<<grid(2LL*NN*32 + 24576),256,0,stream>>>(ei, et, deg, cnt,
        basis0, comp0, basis1,comp1,root1, basis2,comp2,root2,
        basis3,comp3,root3, W0, Wcat);
  k_scan<<<1,256,0,stream>>>(deg, rowptr, cursor);
  k_fill<<<grid(ELL),256,0,stream>>>(ei, et, cursor, pks);

  // ---- RGCN layer 0 (x = I) ----
  k_ragg0<<<dim3((NN+7)/8),256,0,stream>>>(W0, root0, rbias0, rowptr, pks, cnt, xa);

  // ---- RGCN layers 1..3 ----
  k_nodemm<32><<<dim3(750),192,0,stream>>>(xa, Wcat,         H);
  k_ragg<64><<<dim3((NN+3)/4),256,0,stream>>>(H, rbias1, rowptr, pks, cnt, xb);
  k_nodemm<64><<<dim3(750),192,0,stream>>>(xb, Wcat + 6144,  H);
  k_ragg<64><<<dim3((NN+3)/4),256,0,stream>>>(H, rbias2, rowptr, pks, cnt, xa);
  k_nodemm<64><<<dim3(750),192,0,stream>>>(xa, Wcat + 18432, H);
  k_ragg<32><<<dim3((NN+7)/8),256,0,stream>>>(H, rbias3, rowptr, pks, cnt, xb);
  // final RGCN output (N x 32) in xb

  // ---- GAT ----
  k_gat<<<dim3(NN/8),128,0,stream>>>(xb, gat_w, a_src, a_dst, h, asv, adv);
  k_gat_soft<<<dim3((NN+15)/16),256,0,stream>>>(rowptr, pks, asv, adv, coef);
  k_gat_agg<<<dim3(NN),128,0,stream>>>(rowptr, pks, coef, h, gat_b, gout);

  // ---- edge MLP ----
  k_AB<<<dim3(1500),256,0,stream>>>(gout, w1, P);
  k_edge<<<dim3((EE+3)/4),256,0,stream>>>(ei, P, b1, w2, b2, out);
}

// Round 8
// 322.293 us; speedup vs baseline: 5.9181x; 1.0559x over previous
//
#include <hip/hip_runtime.h>
#include <math.h>

#define NN 6000
#define EE 100000
#define ELL (EE + NN)   // edges + self loops for GAT

// packed CSR entry: src (13b) | rel<<13 | self<<14
#define PK_SRC(p)  ((p) & 0x1FFF)
#define PK_REL(p)  (((p) >> 13) & 1)
#define PK_SELF(p) ((p) & 0x4000)

__device__ __forceinline__ unsigned short f2bf(float f){
  unsigned u = __float_as_uint(f);
  unsigned r = u + 0x7FFFu + ((u >> 16) & 1u);   // round-to-nearest-even
  return (unsigned short)(r >> 16);
}
__device__ __forceinline__ float bf2f(unsigned short s){
  return __uint_as_float(((unsigned)s) << 16);
}

// ---- fused: degree + per-relation count + weight prep (independent work) ----
__global__ void k_pdc(const int* __restrict__ ei, const int* __restrict__ et,
                      int* __restrict__ deg, float* __restrict__ cnt,
                      const float* __restrict__ basis0, const float* __restrict__ comp0,
                      const float* __restrict__ b1,const float* __restrict__ c1,const float* __restrict__ r1,
                      const float* __restrict__ b2,const float* __restrict__ c2,const float* __restrict__ r2,
                      const float* __restrict__ b3,const float* __restrict__ c3,const float* __restrict__ r3,
                      float* __restrict__ W0, float* __restrict__ Wcat){
  int t0 = blockIdx.x*256 + threadIdx.x;
  if (t0 < ELL){
    if (t0 < EE){
      int d = ei[EE+t0]; int r = et[t0];
      atomicAdd(&deg[d], 1);
      atomicAdd(&cnt[r*NN+d], 1.0f);
    } else {
      atomicAdd(&deg[t0-EE], 1);
    }
  }
  if (t0 < 2*NN*32){
    int r = t0 / (NN*32);
    int no = t0 - r*(NN*32);
    float acc = 0.f;
    #pragma unroll
    for (int b=0;b<4;b++) acc += comp0[r*4+b] * basis0[b*(NN*32)+no];
    W0[t0] = acc;
    return;
  }
  int tw = t0 - 2*NN*32;
  if (tw >= 24576) return;
  const float *bb,*cc,*rr; int I,O; int t = tw;
  if (tw < 6144)        { bb=b1;cc=c1;rr=r1;I=32;O=64; }
  else if (tw < 18432)  { bb=b2;cc=c2;rr=r2;I=64;O=64; t -= 6144; }
  else                  { bb=b3;cc=c3;rr=r3;I=64;O=32; t -= 18432; }
  int C = 3*O;
  int i = t / C; int col = t - i*C;
  float v;
  if (col < O) v = rr[i*O + col];
  else {
    int r = (col - O) / O; int o = col - O - r*O;
    v = 0.f;
    #pragma unroll
    for (int b=0;b<4;b++) v += cc[r*4+b]*bb[(b*I+i)*O + o];
  }
  Wcat[tw] = v;
}

// single-block exclusive scan over NN=6000 (256 threads x 24 elements)
__global__ void k_scan(const int* __restrict__ deg, int* __restrict__ rowptr,
                       int* __restrict__ cursor){
  __shared__ int ssum[256];
  const int PER = 24;
  int tid = threadIdx.x;
  int base = tid*PER;
  int local[PER];
  int s = 0;
  #pragma unroll
  for (int k=0;k<PER;k++){ int i = base+k; int v = (i<NN)?deg[i]:0; local[k]=s; s+=v; }
  ssum[tid] = s; __syncthreads();
  for (int off=1; off<256; off<<=1){
    int v = (tid>=off) ? ssum[tid-off] : 0;
    __syncthreads();
    ssum[tid] += v;
    __syncthreads();
  }
  int prefix = (tid==0) ? 0 : ssum[tid-1];
  #pragma unroll
  for (int k=0;k<PER;k++){
    int i = base+k;
    if (i<NN){ int v = prefix+local[k]; rowptr[i]=v; cursor[i]=v; }
  }
  if (tid==255) rowptr[NN] = ssum[255];
}

// fill packed-src CSR
__global__ void k_fill(const int* __restrict__ ei, const int* __restrict__ et,
                       int* __restrict__ cursor, int* __restrict__ pks){
  int j = blockIdx.x*256 + threadIdx.x;
  if (j >= ELL) return;
  int d, pk;
  if (j < EE){ d = ei[EE+j]; pk = ei[j] | (et[j] << 13); }
  else       { d = j - EE;   pk = d | 0x4000; }
  int pos = atomicAdd(&cursor[d], 1);
  pks[pos] = pk;
}

// fused layer-0 aggregation + combine + tanh (x = I)
__global__ void k_ragg0(const float* __restrict__ W0, const float* __restrict__ root,
                        const float* __restrict__ rbias,
                        const int* __restrict__ rowptr, const int* __restrict__ pks,
                        const float* __restrict__ cnt, float* __restrict__ xout){
  int n = blockIdx.x*8 + (threadIdx.x >> 5);
  int o = threadIdx.x & 31;
  if (n >= NN) return;
  int r0 = rowptr[n], r1 = rowptr[n+1];
  float a0 = 0.f, a1 = 0.f;
  for (int j=r0;j<r1;j++){
    int p = pks[j];
    if (PK_SELF(p)) continue;
    float v = W0[(PK_REL(p)*NN + PK_SRC(p))*32 + o];
    if (PK_REL(p)==0) a0 += v; else a1 += v;
  }
  float v = root[n*32+o] + rbias[o]
          + a0/fmaxf(cnt[n],1.f) + a1/fmaxf(cnt[NN+n],1.f);
  xout[n*32+o] = tanhf(v);
}

// H = x @ Wcat : [N, 3O] — 8 nodes/block, 192 threads
template<int I>
__global__ void __launch_bounds__(192) k_nodemm(const float* __restrict__ x,
                                                const float* __restrict__ Wc,
                                                float* __restrict__ H){
  __shared__ float sx[8*I];
  int n0 = blockIdx.x*8;
  for (int c = threadIdx.x; c < 8*I; c += 192) sx[c] = x[n0*I + c];
  __syncthreads();
  int c = threadIdx.x;      // 0..191
  float acc[8] = {0,0,0,0,0,0,0,0};
  for (int i=0;i<I;i++){
    float w = Wc[i*192 + c];
    #pragma unroll
    for (int tt=0;tt<8;tt++) acc[tt] += sx[tt*I + i] * w;
  }
  #pragma unroll
  for (int tt=0;tt<8;tt++) H[(n0+tt)*192 + c] = acc[tt];
}

// fused RGCN agg + mean + root + tanh for layers 1..3
template<int O>
__global__ void k_ragg(const float* __restrict__ H, const float* __restrict__ rbias,
                       const int* __restrict__ rowptr, const int* __restrict__ pks,
                       const float* __restrict__ cnt, float* __restrict__ xout){
  constexpr int NPB = 256/O;
  int n = blockIdx.x*NPB + threadIdx.x/O;
  int o = threadIdx.x % O;
  if (n >= NN) return;
  int r0 = rowptr[n], r1 = rowptr[n+1];
  float a0 = 0.f, a1 = 0.f;
  for (int j=r0;j<r1;j++){
    int p = pks[j];
    if (PK_SELF(p)) continue;
    int rel = PK_REL(p);
    float v = H[PK_SRC(p)*3*O + O + rel*O + o];
    if (rel==0) a0 += v; else a1 += v;
  }
  float v = H[n*3*O + o] + rbias[o]
          + a0/fmaxf(cnt[n],1.f) + a1/fmaxf(cnt[NN+n],1.f);
  xout[n*O+o] = tanhf(v);
}

// ---- GAT: h = x@gw (8 nodes/block) fused with per-node scores; h stored bf16 ----
__global__ void k_gat(const float* __restrict__ x, const float* __restrict__ gw,
                      const float* __restrict__ as_, const float* __restrict__ ad_,
                      unsigned short* __restrict__ h16,
                      float* __restrict__ asv, float* __restrict__ adv){
  int n0 = blockIdx.x*8;
  int t = threadIdx.x;  // 128 threads
  __shared__ float sx[8*32];
  __shared__ float red[2][16];
  for (int c=t; c<8*32; c+=128) sx[c] = x[n0*32 + c];
  __syncthreads();
  float4 acc[8];
  #pragma unroll
  for (int k=0;k<8;k++) acc[k] = {0,0,0,0};
  for (int i=0;i<32;i++){
    const float4 g = *(const float4*)&gw[i*512 + t*4];
    #pragma unroll
    for (int k=0;k<8;k++){
      float xv = sx[k*32+i];
      acc[k].x += xv*g.x; acc[k].y += xv*g.y; acc[k].z += xv*g.z; acc[k].w += xv*g.w;
    }
  }
  const float4 a4 = *(const float4*)&as_[t*4];
  const float4 d4 = *(const float4*)&ad_[t*4];
  float sa[8], sd[8];
  #pragma unroll
  for (int k=0;k<8;k++){
    ushort4 o;
    o.x = f2bf(acc[k].x); o.y = f2bf(acc[k].y);
    o.z = f2bf(acc[k].z); o.w = f2bf(acc[k].w);
    *(ushort4*)&h16[(n0+k)*512 + t*4] = o;
    sa[k] = acc[k].x*a4.x + acc[k].y*a4.y + acc[k].z*a4.z + acc[k].w*a4.w;
    sd[k] = acc[k].x*d4.x + acc[k].y*d4.y + acc[k].z*d4.z + acc[k].w*d4.w;
  }
  #pragma unroll
  for (int m=32;m>0;m>>=1){
    #pragma unroll
    for (int k=0;k<8;k++){ sa[k] += __shfl_xor(sa[k],m,64); sd[k] += __shfl_xor(sd[k],m,64); }
  }
  int wv = t>>6;
  if ((t&63)==0){
    #pragma unroll
    for (int k=0;k<8;k++){ red[wv][k]=sa[k]; red[wv][8+k]=sd[k]; }
  }
  __syncthreads();
  if (t<8)              asv[n0+t]   = red[0][t]+red[1][t];
  else if (t<16)        adv[n0+t-8] = red[0][t]+red[1][t];
}

// per-node softmax, 16 lanes per node (deg ~17.7), ex cached in coef
__global__ void k_gat_soft(const int* __restrict__ rowptr, const int* __restrict__ pks,
                           const float* __restrict__ asv, const float* __restrict__ adv,
                           float* __restrict__ coef){
  int n = blockIdx.x*16 + (threadIdx.x >> 4);
  int lane = threadIdx.x & 15;
  if (n >= NN) return;
  int r0 = rowptr[n], r1 = rowptr[n+1];
  float advn = adv[n];
  float m = -1e30f;
  for (int j=r0+lane; j<r1; j+=16){
    float a = asv[PK_SRC(pks[j])] + advn; a = (a>=0.f)? a : 0.2f*a;
    m = fmaxf(m, a);
  }
  #pragma unroll
  for (int off=8;off>0;off>>=1) m = fmaxf(m, __shfl_xor(m,off,64));
  float sum = 0.f;
  for (int j=r0+lane; j<r1; j+=16){
    float a = asv[PK_SRC(pks[j])] + advn; a = (a>=0.f)? a : 0.2f*a;
    float ex = expf(a - m);
    coef[j] = ex;
    sum += ex;
  }
  #pragma unroll
  for (int off=8;off>0;off>>=1) sum += __shfl_xor(sum,off,64);
  float inv = 1.f / fmaxf(sum, 1e-16f);
  for (int j=r0+lane; j<r1; j+=16) coef[j] *= inv;
}

// per-node gather aggregation (bf16 h) + bias + relu
__global__ void k_gat_agg(const int* __restrict__ rowptr, const int* __restrict__ pks,
                          const float* __restrict__ coef, const unsigned short* __restrict__ h16,
                          const float* __restrict__ bias, float* __restrict__ gout){
  int n = blockIdx.x;
  int c = threadIdx.x;             // 128 threads * 4 ch = 512 channels
  int r0 = rowptr[n], r1 = rowptr[n+1];
  float4 acc = {0.f,0.f,0.f,0.f};
  int j = r0;
  for (; j+2<=r1; j+=2){
    int p0 = pks[j], p1 = pks[j+1];
    float c0 = coef[j], c1 = coef[j+1];
    const ushort4 h0 = *(const ushort4*)&h16[PK_SRC(p0)*512 + c*4];
    const ushort4 h1 = *(const ushort4*)&h16[PK_SRC(p1)*512 + c*4];
    acc.x += c0*bf2f(h0.x) + c1*bf2f(h1.x);
    acc.y += c0*bf2f(h0.y) + c1*bf2f(h1.y);
    acc.z += c0*bf2f(h0.z) + c1*bf2f(h1.z);
    acc.w += c0*bf2f(h0.w) + c1*bf2f(h1.w);
  }
  if (j < r1){
    int p0 = pks[j]; float c0 = coef[j];
    const ushort4 h0 = *(const ushort4*)&h16[PK_SRC(p0)*512 + c*4];
    acc.x += c0*bf2f(h0.x); acc.y += c0*bf2f(h0.y);
    acc.z += c0*bf2f(h0.z); acc.w += c0*bf2f(h0.w);
  }
  const float4 b = *(const float4*)&bias[c*4];
  float4 o;
  o.x = fmaxf(acc.x+b.x, 0.f); o.y = fmaxf(acc.y+b.y, 0.f);
  o.z = fmaxf(acc.z+b.z, 0.f); o.w = fmaxf(acc.w+b.w, 0.f);
  *(float4*)&gout[n*512 + c*4] = o;
}

// ---- edge MLP precompute, split-K=2, 2 cols/thread ----
// 1500 blocks (750 tiles x 2 kh), 128 threads; thread = 2 consecutive cols x 8 nodes
__global__ void __launch_bounds__(128) k_AB(const float* __restrict__ x5,
                                            const float* __restrict__ w1,
                                            float* __restrict__ P){
  __shared__ float sx[8*256];   // 8 KB: 8 nodes x 256 k (this half)
  int b = blockIdx.x;
  int tile = b >> 1, kh = b & 1;
  int n0 = tile*8;
  {
    float4* dst = (float4*)sx;
    for (int q = threadIdx.x; q < 8*64; q += 128){
      int node = q >> 6, kq = q & 63;
      dst[q] = *(const float4*)&x5[(n0+node)*512 + kh*256 + kq*4];
    }
  }
  __syncthreads();
  int half = threadIdx.x >> 6;         // 0 -> A, 1 -> B
  int c    = threadIdx.x & 63;         // col pair: cols 2c, 2c+1
  const float* wcol = w1 + (size_t)half*512*128 + (size_t)(kh*256)*128 + 2*c;
  float accx[8] = {0,0,0,0,0,0,0,0};
  float accy[8] = {0,0,0,0,0,0,0,0};
  for (int k4=0;k4<64;k4++){
    const float2 w0 = *(const float2*)(wcol + (k4*4+0)*128);
    const float2 w1v= *(const float2*)(wcol + (k4*4+1)*128);
    const float2 w2v= *(const float2*)(wcol + (k4*4+2)*128);
    const float2 w3v= *(const float2*)(wcol + (k4*4+3)*128);
    #pragma unroll
    for (int tt=0;tt<8;tt++){
      const float4 xv = *(const float4*)&sx[tt*256 + k4*4];
      accx[tt] += xv.x*w0.x + xv.y*w1v.x + xv.z*w2v.x + xv.w*w3v.x;
      accy[tt] += xv.x*w0.y + xv.y*w1v.y + xv.z*w2v.y + xv.w*w3v.y;
    }
  }
  // P[kh][node][col] with col = half*128 + 2c (+1)
  float* dst = P + (size_t)kh*NN*256;
  int col = half*128 + 2*c;
  #pragma unroll
  for (int tt=0;tt<8;tt++){
    float2 o = {accx[tt], accy[tt]};
    *(float2*)&dst[(n0+tt)*256 + col] = o;
  }
}

// per-edge MLP head: 16 lanes/edge, float4 loads, 4-step reduce
__global__ void k_edge(const int* __restrict__ ei, const float* __restrict__ P,
                       const float* __restrict__ b1,
                       const float* __restrict__ w2, const float* __restrict__ b2,
                       float* __restrict__ out){
  int e = blockIdx.x*16 + (threadIdx.x >> 4);
  int l = threadIdx.x & 15;            // lane covers channels [l*8, l*8+8)
  if (e >= EE) return;
  int s = ei[e], d = ei[EE+e];
  const float4 b1a = *(const float4*)&b1[l*8];
  const float4 b1b = *(const float4*)&b1[l*8+4];
  const float4 w2a = *(const float4*)&w2[l*8];
  const float4 w2b = *(const float4*)&w2[l*8+4];
  const float4 A00 = *(const float4*)&P[s*256 + l*8];
  const float4 A01 = *(const float4*)&P[s*256 + l*8 + 4];
  const float4 A10 = *(const float4*)&P[(size_t)NN*256 + s*256 + l*8];
  const float4 A11 = *(const float4*)&P[(size_t)NN*256 + s*256 + l*8 + 4];
  const float4 B00 = *(const float4*)&P[d*256 + 128 + l*8];
  const float4 B01 = *(const float4*)&P[d*256 + 128 + l*8 + 4];
  const float4 B10 = *(const float4*)&P[(size_t)NN*256 + d*256 + 128 + l*8];
  const float4 B11 = *(const float4*)&P[(size_t)NN*256 + d*256 + 128 + l*8 + 4];
  float acc;
  {
    float h0 = fmaxf(A00.x+A10.x+B00.x+B10.x+b1a.x, 0.f);
    float h1 = fmaxf(A00.y+A10.y+B00.y+B10.y+b1a.y, 0.f);
    float h2 = fmaxf(A00.z+A10.z+B00.z+B10.z+b1a.z, 0.f);
    float h3 = fmaxf(A00.w+A10.w+B00.w+B10.w+b1a.w, 0.f);
    float h4 = fmaxf(A01.x+A11.x+B01.x+B11.x+b1b.x, 0.f);
    float h5 = fmaxf(A01.y+A11.y+B01.y+B11.y+b1b.y, 0.f);
    float h6 = fmaxf(A01.z+A11.z+B01.z+B11.z+b1b.z, 0.f);
    float h7 = fmaxf(A01.w+A11.w+B01.w+B11.w+b1b.w, 0.f);
    acc = h0*w2a.x + h1*w2a.y + h2*w2a.z + h3*w2a.w
        + h4*w2b.x + h5*w2b.y + h6*w2b.z + h7*w2b.w;
  }
  #pragma unroll
  for (int m=8;m>0;m>>=1) acc += __shfl_xor(acc,m,64);
  if (l==0) out[e] = 1.f/(1.f + expf(-(acc + b2[0])));
}

extern "C" void kernel_launch(void* const* d_in, const int* in_sizes, int n_in,
                              void* d_out, int out_size, void* d_ws, size_t ws_size,
                              hipStream_t stream){
  const float* basis0 = (const float*)d_in[0];
  const float* comp0  = (const float*)d_in[1];
  const float* root0  = (const float*)d_in[2];
  const float* rbias0 = (const float*)d_in[3];
  const float* basis1 = (const float*)d_in[4];
  const float* comp1  = (const float*)d_in[5];
  const float* root1  = (const float*)d_in[6];
  const float* rbias1 = (const float*)d_in[7];
  const float* basis2 = (const float*)d_in[8];
  const float* comp2  = (const float*)d_in[9];
  const float* root2  = (const float*)d_in[10];
  const float* rbias2 = (const float*)d_in[11];
  const float* basis3 = (const float*)d_in[12];
  const float* comp3  = (const float*)d_in[13];
  const float* root3  = (const float*)d_in[14];
  const float* rbias3 = (const float*)d_in[15];
  const float* gat_w = (const float*)d_in[16];
  const float* a_src = (const float*)d_in[17];
  const float* a_dst = (const float*)d_in[18];
  const float* gat_b = (const float*)d_in[19];
  const float* w1 = (const float*)d_in[20];
  const float* b1 = (const float*)d_in[21];
  const float* w2 = (const float*)d_in[22];
  const float* b2 = (const float*)d_in[23];
  const int* ei = (const int*)d_in[24];
  const int* et = (const int*)d_in[25];
  float* out = (float*)d_out;

  // workspace carve-up (deg+cnt adjacent: one memset)
  float* p = (float*)d_ws;
  int* deg    = (int*)p; p += NN;
  float* cnt  = p; p += 2*NN;
  int* rowptr = (int*)p; p += NN+4;
  int* cursor = (int*)p; p += NN;
  int* pks    = (int*)p; p += ELL + 2;
  float* W0   = p; p += 2*NN*32;
  float* Wcat = p; p += 24576;
  float* xa   = p; p += NN*64;
  float* xb   = p; p += NN*64;
  float* H    = p; p += NN*192;
  unsigned short* h16 = (unsigned short*)p; p += NN*256;   // NN*512 bf16
  float* asv  = p; p += NN;
  float* adv  = p; p += NN;
  float* coef = p; p += ELL + 2;
  float* gout = p; p += NN*512;
  float* P    = p; p += 2*NN*256;

  auto grid = [](long long n){ return dim3((unsigned)((n + 255)/256)); };

  // ---- CSR build + weight prep (fused) ----
  hipMemsetAsync(deg, 0, (size_t)3*NN*sizeof(int), stream);  // deg + cnt
  k_pdc<<<grid(2LL*NN*32 + 24576),256,0,stream>>>(ei, et, deg, cnt,
        basis0, comp0, basis1,comp1,root1, basis2,comp2,root2,
        basis3,comp3,root3, W0, Wcat);
  k_scan<<<1,256,0,stream>>>(deg, rowptr, cursor);
  k_fill<<<grid(ELL),256,0,stream>>>(ei, et, cursor, pks);

  // ---- RGCN layer 0 (x = I) ----
  k_ragg0<<<dim3((NN+7)/8),256,0,stream>>>(W0, root0, rbias0, rowptr, pks, cnt, xa);

  // ---- RGCN layers 1..3 ----
  k_nodemm<32><<<dim3(750),192,0,stream>>>(xa, Wcat,         H);
  k_ragg<64><<<dim3((NN+3)/4),256,0,stream>>>(H, rbias1, rowptr, pks, cnt, xb);
  k_nodemm<64><<<dim3(750),192,0,stream>>>(xb, Wcat + 6144,  H);
  k_ragg<64><<<dim3((NN+3)/4),256,0,stream>>>(H, rbias2, rowptr, pks, cnt, xa);
  k_nodemm<64><<<dim3(750),192,0,stream>>>(xa, Wcat + 18432, H);
  k_ragg<32><<<dim3((NN+7)/8),256,0,stream>>>(H, rbias3, rowptr, pks, cnt, xb);
  // final RGCN output (N x 32) in xb

  // ---- GAT ----
  k_gat<<<dim3(NN/8),128,0,stream>>>(xb, gat_w, a_src, a_dst, h16, asv, adv);
  k_gat_soft<<<dim3((NN+15)/16),256,0,stream>>>(rowptr, pks, asv, adv, coef);
  k_gat_agg<<<dim3(NN),128,0,stream>>>(rowptr, pks, coef, h16, gat_b, gout);

  // ---- edge MLP ----
  k_AB<<<dim3(1500),128,0,stream>>>(gout, w1, P);
  k_edge<<<dim3((EE+15)/16),256,0,stream>>>(ei, P, b1, w2, b2, out);
}

// Round 9
// 289.281 us; speedup vs baseline: 6.5934x; 1.1141x over previous
//
#include <hip/hip_runtime.h>
#include <math.h>

#define NN 6000
#define EE 100000
#define ELL (EE + NN)   // edges + self loops for GAT

// packed CSR entry: src (13b) | rel<<13 | self<<14
#define PK_SRC(p)  ((p) & 0x1FFF)
#define PK_REL(p)  (((p) >> 13) & 1)
#define PK_SELF(p) ((p) & 0x4000)

typedef __attribute__((ext_vector_type(8))) short frag8;   // 8 bf16 (4 VGPR)
typedef __attribute__((ext_vector_type(4))) float f32x4;

__device__ __forceinline__ unsigned short f2bf(float f){
  unsigned u = __float_as_uint(f);
  unsigned r = u + 0x7FFFu + ((u >> 16) & 1u);   // round-to-nearest-even
  return (unsigned short)(r >> 16);
}
__device__ __forceinline__ float bf2f(unsigned short s){
  return __uint_as_float(((unsigned)s) << 16);
}

// ---- fused: degree/count + weight prep + w1->Bt bf16 transpose ----
__global__ void k_pdc(const int* __restrict__ ei, const int* __restrict__ et,
                      int* __restrict__ deg, float* __restrict__ cnt,
                      const float* __restrict__ basis0, const float* __restrict__ comp0,
                      const float* __restrict__ b1,const float* __restrict__ c1,const float* __restrict__ r1,
                      const float* __restrict__ b2,const float* __restrict__ c2,const float* __restrict__ r2,
                      const float* __restrict__ b3,const float* __restrict__ c3,const float* __restrict__ r3,
                      const float* __restrict__ w1,
                      float* __restrict__ W0, float* __restrict__ Wcat,
                      unsigned short* __restrict__ Bt16){
  int t0 = blockIdx.x*256 + threadIdx.x;
  if (t0 < ELL){
    if (t0 < EE){
      int d = ei[EE+t0]; int r = et[t0];
      atomicAdd(&deg[d], 1);
      atomicAdd(&cnt[r*NN+d], 1.0f);
    } else {
      atomicAdd(&deg[t0-EE], 1);
    }
  }
  if (t0 < 2*NN*32){
    int r = t0 / (NN*32);
    int no = t0 - r*(NN*32);
    float acc = 0.f;
    #pragma unroll
    for (int b=0;b<4;b++) acc += comp0[r*4+b] * basis0[b*(NN*32)+no];
    W0[t0] = acc;
    return;
  }
  int tw = t0 - 2*NN*32;
  if (tw < 24576){
    const float *bb,*cc,*rr; int I,O; int t = tw;
    if (tw < 6144)        { bb=b1;cc=c1;rr=r1;I=32;O=64; }
    else if (tw < 18432)  { bb=b2;cc=c2;rr=r2;I=64;O=64; t -= 6144; }
    else                  { bb=b3;cc=c3;rr=r3;I=64;O=32; t -= 18432; }
    int C = 3*O;
    int i = t / C; int col = t - i*C;
    float v;
    if (col < O) v = rr[i*O + col];
    else {
      int r = (col - O) / O; int o = col - O - r*O;
      v = 0.f;
      #pragma unroll
      for (int b=0;b<4;b++) v += cc[r*4+b]*bb[(b*I+i)*O + o];
    }
    Wcat[tw] = v;
    return;
  }
  int tb = tw - 24576;           // Bt16: [n][k], n in [0,256), k in [0,512)
  if (tb >= 256*512) return;
  int n = tb >> 9, k = tb & 511;
  float v = (n < 128) ? w1[k*128 + n] : w1[(512+k)*128 + (n-128)];
  Bt16[tb] = f2bf(v);
}

// single-block exclusive scan over NN=6000 (256 threads x 24 elements)
__global__ void k_scan(const int* __restrict__ deg, int* __restrict__ rowptr,
                       int* __restrict__ cursor){
  __shared__ int ssum[256];
  const int PER = 24;
  int tid = threadIdx.x;
  int base = tid*PER;
  int local[PER];
  int s = 0;
  #pragma unroll
  for (int k=0;k<PER;k++){ int i = base+k; int v = (i<NN)?deg[i]:0; local[k]=s; s+=v; }
  ssum[tid] = s; __syncthreads();
  for (int off=1; off<256; off<<=1){
    int v = (tid>=off) ? ssum[tid-off] : 0;
    __syncthreads();
    ssum[tid] += v;
    __syncthreads();
  }
  int prefix = (tid==0) ? 0 : ssum[tid-1];
  #pragma unroll
  for (int k=0;k<PER;k++){
    int i = base+k;
    if (i<NN){ int v = prefix+local[k]; rowptr[i]=v; cursor[i]=v; }
  }
  if (tid==255) rowptr[NN] = ssum[255];
}

// fill packed-src CSR
__global__ void k_fill(const int* __restrict__ ei, const int* __restrict__ et,
                       int* __restrict__ cursor, int* __restrict__ pks){
  int j = blockIdx.x*256 + threadIdx.x;
  if (j >= ELL) return;
  int d, pk;
  if (j < EE){ d = ei[EE+j]; pk = ei[j] | (et[j] << 13); }
  else       { d = j - EE;   pk = d | 0x4000; }
  int pos = atomicAdd(&cursor[d], 1);
  pks[pos] = pk;
}

// fused layer-0 aggregation + combine + tanh (x = I)
__global__ void k_ragg0(const float* __restrict__ W0, const float* __restrict__ root,
                        const float* __restrict__ rbias,
                        const int* __restrict__ rowptr, const int* __restrict__ pks,
                        const float* __restrict__ cnt, float* __restrict__ xout){
  int n = blockIdx.x*8 + (threadIdx.x >> 5);
  int o = threadIdx.x & 31;
  if (n >= NN) return;
  int r0 = rowptr[n], r1 = rowptr[n+1];
  float a0 = 0.f, a1 = 0.f;
  for (int j=r0;j<r1;j++){
    int p = pks[j];
    if (PK_SELF(p)) continue;
    float v = W0[(PK_REL(p)*NN + PK_SRC(p))*32 + o];
    if (PK_REL(p)==0) a0 += v; else a1 += v;
  }
  float v = root[n*32+o] + rbias[o]
          + a0/fmaxf(cnt[n],1.f) + a1/fmaxf(cnt[NN+n],1.f);
  xout[n*32+o] = tanhf(v);
}

// H = x @ Wcat : [N, 3O] — 8 nodes/block, 192 threads
template<int I>
__global__ void __launch_bounds__(192) k_nodemm(const float* __restrict__ x,
                                                const float* __restrict__ Wc,
                                                float* __restrict__ H){
  __shared__ float sx[8*I];
  int n0 = blockIdx.x*8;
  for (int c = threadIdx.x; c < 8*I; c += 192) sx[c] = x[n0*I + c];
  __syncthreads();
  int c = threadIdx.x;      // 0..191
  float acc[8] = {0,0,0,0,0,0,0,0};
  for (int i=0;i<I;i++){
    float w = Wc[i*192 + c];
    #pragma unroll
    for (int tt=0;tt<8;tt++) acc[tt] += sx[tt*I + i] * w;
  }
  #pragma unroll
  for (int tt=0;tt<8;tt++) H[(n0+tt)*192 + c] = acc[tt];
}

// fused RGCN agg + mean + root + tanh for layers 1..3
template<int O>
__global__ void k_ragg(const float* __restrict__ H, const float* __restrict__ rbias,
                       const int* __restrict__ rowptr, const int* __restrict__ pks,
                       const float* __restrict__ cnt, float* __restrict__ xout){
  constexpr int NPB = 256/O;
  int n = blockIdx.x*NPB + threadIdx.x/O;
  int o = threadIdx.x % O;
  if (n >= NN) return;
  int r0 = rowptr[n], r1 = rowptr[n+1];
  float a0 = 0.f, a1 = 0.f;
  for (int j=r0;j<r1;j++){
    int p = pks[j];
    if (PK_SELF(p)) continue;
    int rel = PK_REL(p);
    float v = H[PK_SRC(p)*3*O + O + rel*O + o];
    if (rel==0) a0 += v; else a1 += v;
  }
  float v = H[n*3*O + o] + rbias[o]
          + a0/fmaxf(cnt[n],1.f) + a1/fmaxf(cnt[NN+n],1.f);
  xout[n*O+o] = tanhf(v);
}

// ---- GAT: h = x@gw (8 nodes/block) fused with per-node scores; h stored bf16 ----
__global__ void k_gat(const float* __restrict__ x, const float* __restrict__ gw,
                      const float* __restrict__ as_, const float* __restrict__ ad_,
                      unsigned short* __restrict__ h16,
                      float* __restrict__ asv, float* __restrict__ adv){
  int n0 = blockIdx.x*8;
  int t = threadIdx.x;  // 128 threads
  __shared__ float sx[8*32];
  __shared__ float red[2][16];
  for (int c=t; c<8*32; c+=128) sx[c] = x[n0*32 + c];
  __syncthreads();
  float4 acc[8];
  #pragma unroll
  for (int k=0;k<8;k++) acc[k] = {0,0,0,0};
  for (int i=0;i<32;i++){
    const float4 g = *(const float4*)&gw[i*512 + t*4];
    #pragma unroll
    for (int k=0;k<8;k++){
      float xv = sx[k*32+i];
      acc[k].x += xv*g.x; acc[k].y += xv*g.y; acc[k].z += xv*g.z; acc[k].w += xv*g.w;
    }
  }
  const float4 a4 = *(const float4*)&as_[t*4];
  const float4 d4 = *(const float4*)&ad_[t*4];
  float sa[8], sd[8];
  #pragma unroll
  for (int k=0;k<8;k++){
    ushort4 o;
    o.x = f2bf(acc[k].x); o.y = f2bf(acc[k].y);
    o.z = f2bf(acc[k].z); o.w = f2bf(acc[k].w);
    *(ushort4*)&h16[(n0+k)*512 + t*4] = o;
    sa[k] = acc[k].x*a4.x + acc[k].y*a4.y + acc[k].z*a4.z + acc[k].w*a4.w;
    sd[k] = acc[k].x*d4.x + acc[k].y*d4.y + acc[k].z*d4.z + acc[k].w*d4.w;
  }
  #pragma unroll
  for (int m=32;m>0;m>>=1){
    #pragma unroll
    for (int k=0;k<8;k++){ sa[k] += __shfl_xor(sa[k],m,64); sd[k] += __shfl_xor(sd[k],m,64); }
  }
  int wv = t>>6;
  if ((t&63)==0){
    #pragma unroll
    for (int k=0;k<8;k++){ red[wv][k]=sa[k]; red[wv][8+k]=sd[k]; }
  }
  __syncthreads();
  if (t<8)              asv[n0+t]   = red[0][t]+red[1][t];
  else if (t<16)        adv[n0+t-8] = red[0][t]+red[1][t];
}

// per-node softmax, 16 lanes per node (deg ~17.7), ex cached in coef
__global__ void k_gat_soft(const int* __restrict__ rowptr, const int* __restrict__ pks,
                           const float* __restrict__ asv, const float* __restrict__ adv,
                           float* __restrict__ coef){
  int n = blockIdx.x*16 + (threadIdx.x >> 4);
  int lane = threadIdx.x & 15;
  if (n >= NN) return;
  int r0 = rowptr[n], r1 = rowptr[n+1];
  float advn = adv[n];
  float m = -1e30f;
  for (int j=r0+lane; j<r1; j+=16){
    float a = asv[PK_SRC(pks[j])] + advn; a = (a>=0.f)? a : 0.2f*a;
    m = fmaxf(m, a);
  }
  #pragma unroll
  for (int off=8;off>0;off>>=1) m = fmaxf(m, __shfl_xor(m,off,64));
  float sum = 0.f;
  for (int j=r0+lane; j<r1; j+=16){
    float a = asv[PK_SRC(pks[j])] + advn; a = (a>=0.f)? a : 0.2f*a;
    float ex = expf(a - m);
    coef[j] = ex;
    sum += ex;
  }
  #pragma unroll
  for (int off=8;off>0;off>>=1) sum += __shfl_xor(sum,off,64);
  float inv = 1.f / fmaxf(sum, 1e-16f);
  for (int j=r0+lane; j<r1; j+=16) coef[j] *= inv;
}

// per-node gather aggregation (bf16 h) + bias + relu; writes bf16 gout
__global__ void k_gat_agg(const int* __restrict__ rowptr, const int* __restrict__ pks,
                          const float* __restrict__ coef, const unsigned short* __restrict__ h16,
                          const float* __restrict__ bias, unsigned short* __restrict__ gout16){
  int n = blockIdx.x;
  int c = threadIdx.x;             // 128 threads * 4 ch = 512 channels
  int r0 = rowptr[n], r1 = rowptr[n+1];
  float4 acc = {0.f,0.f,0.f,0.f};
  int j = r0;
  for (; j+2<=r1; j+=2){
    int p0 = pks[j], p1 = pks[j+1];
    float c0 = coef[j], c1 = coef[j+1];
    const ushort4 h0 = *(const ushort4*)&h16[PK_SRC(p0)*512 + c*4];
    const ushort4 h1 = *(const ushort4*)&h16[PK_SRC(p1)*512 + c*4];
    acc.x += c0*bf2f(h0.x) + c1*bf2f(h1.x);
    acc.y += c0*bf2f(h0.y) + c1*bf2f(h1.y);
    acc.z += c0*bf2f(h0.z) + c1*bf2f(h1.z);
    acc.w += c0*bf2f(h0.w) + c1*bf2f(h1.w);
  }
  if (j < r1){
    int p0 = pks[j]; float c0 = coef[j];
    const ushort4 h0 = *(const ushort4*)&h16[PK_SRC(p0)*512 + c*4];
    acc.x += c0*bf2f(h0.x); acc.y += c0*bf2f(h0.y);
    acc.z += c0*bf2f(h0.z); acc.w += c0*bf2f(h0.w);
  }
  const float4 b = *(const float4*)&bias[c*4];
  ushort4 o;
  o.x = f2bf(fmaxf(acc.x+b.x, 0.f)); o.y = f2bf(fmaxf(acc.y+b.y, 0.f));
  o.z = f2bf(fmaxf(acc.z+b.z, 0.f)); o.w = f2bf(fmaxf(acc.w+b.w, 0.f));
  *(ushort4*)&gout16[n*512 + c*4] = o;
}

// ---- edge MLP precompute via MFMA: P[6000][256] = gout16 @ Bt16^T ----
// 1500 blocks x 64 threads (1 wave). Wave = 16 rows x 64 cols.
// A frag: A[m=lane&15][k=quad*8+j]; B frag from Bt[n][k] (same contiguous-k load).
// C/D: col=lane&15, row=quad*4+reg.
__global__ void __launch_bounds__(64) k_AB(const unsigned short* __restrict__ gout16,
                                           const unsigned short* __restrict__ Bt16,
                                           float* __restrict__ P){
  int lane = threadIdx.x;
  int mt = blockIdx.x >> 2;        // 375 row tiles
  int nt = blockIdx.x & 3;         // 4 col groups of 64
  int kq = (lane >> 4) * 8;
  const unsigned short* arow = gout16 + (size_t)(mt*16 + (lane & 15))*512 + kq;
  const unsigned short* bbase = Bt16 + (size_t)(nt*64 + (lane & 15))*512 + kq;
  f32x4 acc0 = {0,0,0,0}, acc1 = {0,0,0,0}, acc2 = {0,0,0,0}, acc3 = {0,0,0,0};
  for (int k = 0; k < 512; k += 32){
    frag8 a = *(const frag8*)(arow + k);
    frag8 b0 = *(const frag8*)(bbase + k);
    frag8 b1 = *(const frag8*)(bbase + 16*512 + k);
    frag8 b2 = *(const frag8*)(bbase + 32*512 + k);
    frag8 b3 = *(const frag8*)(bbase + 48*512 + k);
    acc0 = __builtin_amdgcn_mfma_f32_16x16x32_bf16(a, b0, acc0, 0, 0, 0);
    acc1 = __builtin_amdgcn_mfma_f32_16x16x32_bf16(a, b1, acc1, 0, 0, 0);
    acc2 = __builtin_amdgcn_mfma_f32_16x16x32_bf16(a, b2, acc2, 0, 0, 0);
    acc3 = __builtin_amdgcn_mfma_f32_16x16x32_bf16(a, b3, acc3, 0, 0, 0);
  }
  int rowb = mt*16 + (lane >> 4)*4;
  int col  = nt*64 + (lane & 15);
  #pragma unroll
  for (int i=0;i<4;i++){
    P[(size_t)(rowb+i)*256 + col     ] = acc0[i];
    P[(size_t)(rowb+i)*256 + col + 16] = acc1[i];
    P[(size_t)(rowb+i)*256 + col + 32] = acc2[i];
    P[(size_t)(rowb+i)*256 + col + 48] = acc3[i];
  }
}

// per-edge MLP head: 16 lanes/edge, float4 loads, 4-step reduce
__global__ void k_edge(const int* __restrict__ ei, const float* __restrict__ P,
                       const float* __restrict__ b1,
                       const float* __restrict__ w2, const float* __restrict__ b2,
                       float* __restrict__ out){
  int e = blockIdx.x*16 + (threadIdx.x >> 4);
  int l = threadIdx.x & 15;            // lane covers channels [l*8, l*8+8)
  if (e >= EE) return;
  int s = ei[e], d = ei[EE+e];
  const float4 b1a = *(const float4*)&b1[l*8];
  const float4 b1b = *(const float4*)&b1[l*8+4];
  const float4 w2a = *(const float4*)&w2[l*8];
  const float4 w2b = *(const float4*)&w2[l*8+4];
  const float4 A0 = *(const float4*)&P[s*256 + l*8];
  const float4 A1 = *(const float4*)&P[s*256 + l*8 + 4];
  const float4 B0 = *(const float4*)&P[d*256 + 128 + l*8];
  const float4 B1 = *(const float4*)&P[d*256 + 128 + l*8 + 4];
  float h0 = fmaxf(A0.x+B0.x+b1a.x, 0.f);
  float h1 = fmaxf(A0.y+B0.y+b1a.y, 0.f);
  float h2 = fmaxf(A0.z+B0.z+b1a.z, 0.f);
  float h3 = fmaxf(A0.w+B0.w+b1a.w, 0.f);
  float h4 = fmaxf(A1.x+B1.x+b1b.x, 0.f);
  float h5 = fmaxf(A1.y+B1.y+b1b.y, 0.f);
  float h6 = fmaxf(A1.z+B1.z+b1b.z, 0.f);
  float h7 = fmaxf(A1.w+B1.w+b1b.w, 0.f);
  float acc = h0*w2a.x + h1*w2a.y + h2*w2a.z + h3*w2a.w
            + h4*w2b.x + h5*w2b.y + h6*w2b.z + h7*w2b.w;
  #pragma unroll
  for (int m=8;m>0;m>>=1) acc += __shfl_xor(acc,m,64);
  if (l==0) out[e] = 1.f/(1.f + expf(-(acc + b2[0])));
}

extern "C" void kernel_launch(void* const* d_in, const int* in_sizes, int n_in,
                              void* d_out, int out_size, void* d_ws, size_t ws_size,
                              hipStream_t stream){
  const float* basis0 = (const float*)d_in[0];
  const float* comp0  = (const float*)d_in[1];
  const float* root0  = (const float*)d_in[2];
  const float* rbias0 = (const float*)d_in[3];
  const float* basis1 = (const float*)d_in[4];
  const float* comp1  = (const float*)d_in[5];
  const float* root1  = (const float*)d_in[6];
  const float* rbias1 = (const float*)d_in[7];
  const float* basis2 = (const float*)d_in[8];
  const float* comp2  = (const float*)d_in[9];
  const float* root2  = (const float*)d_in[10];
  const float* rbias2 = (const float*)d_in[11];
  const float* basis3 = (const float*)d_in[12];
  const float* comp3  = (const float*)d_in[13];
  const float* root3  = (const float*)d_in[14];
  const float* rbias3 = (const float*)d_in[15];
  const float* gat_w = (const float*)d_in[16];
  const float* a_src = (const float*)d_in[17];
  const float* a_dst = (const float*)d_in[18];
  const float* gat_b = (const float*)d_in[19];
  const float* w1 = (const float*)d_in[20];
  const float* b1 = (const float*)d_in[21];
  const float* w2 = (const float*)d_in[22];
  const float* b2 = (const float*)d_in[23];
  const int* ei = (const int*)d_in[24];
  const int* et = (const int*)d_in[25];
  float* out = (float*)d_out;

  // workspace carve-up (all sections 16B-aligned; deg+cnt adjacent: one memset)
  float* p = (float*)d_ws;
  int* deg    = (int*)p; p += NN;              // 6000
  float* cnt  = p; p += 2*NN;                  // 12000
  int* rowptr = (int*)p; p += NN+4;            // 6004
  int* cursor = (int*)p; p += NN;              // 6000
  int* pks    = (int*)p; p += ELL + 4;         // 106004  (sum: 136008, %4==0)
  float* W0   = p; p += 2*NN*32;
  float* Wcat = p; p += 24576;
  unsigned short* Bt16 = (unsigned short*)p; p += 256*512/2;   // 65536 floats
  float* xa   = p; p += NN*64;
  float* xb   = p; p += NN*64;
  float* H    = p; p += NN*192;
  unsigned short* h16 = (unsigned short*)p; p += NN*256;       // NN*512 bf16
  float* asv  = p; p += NN;
  float* adv  = p; p += NN;
  float* coef = p; p += ELL + 4;
  unsigned short* gout16 = (unsigned short*)p; p += NN*256;    // NN*512 bf16
  float* P    = p; p += NN*256;

  auto grid = [](long long n){ return dim3((unsigned)((n + 255)/256)); };

  // ---- CSR build + weight prep + Bt16 (fused) ----
  hipMemsetAsync(deg, 0, (size_t)3*NN*sizeof(int), stream);  // deg + cnt
  k_pdc<<<grid(2LL*NN*32 + 24576 + 256*512),256,0,stream>>>(ei, et, deg, cnt,
        basis0, comp0, basis1,comp1,root1, basis2,comp2,root2,
        basis3,comp3,root3, w1, W0, Wcat, Bt16);
  k_scan<<<1,256,0,stream>>>(deg, rowptr, cursor);
  k_fill<<<grid(ELL),256,0,stream>>>(ei, et, cursor, pks);

  // ---- RGCN layer 0 (x = I) ----
  k_ragg0<<<dim3((NN+7)/8),256,0,stream>>>(W0, root0, rbias0, rowptr, pks, cnt, xa);

  // ---- RGCN layers 1..3 ----
  k_nodemm<32><<<dim3(750),192,0,stream>>>(xa, Wcat,         H);
  k_ragg<64><<<dim3((NN+3)/4),256,0,stream>>>(H, rbias1, rowptr, pks, cnt, xb);
  k_nodemm<64><<<dim3(750),192,0,stream>>>(xb, Wcat + 6144,  H);
  k_ragg<64><<<dim3((NN+3)/4),256,0,stream>>>(H, rbias2, rowptr, pks, cnt, xa);
  k_nodemm<64><<<dim3(750),192,0,stream>>>(xa, Wcat + 18432, H);
  k_ragg<32><<<dim3((NN+7)/8),256,0,stream>>>(H, rbias3, rowptr, pks, cnt, xb);
  // final RGCN output (N x 32) in xb

  // ---- GAT ----
  k_gat<<<dim3(NN/8),128,0,stream>>>(xb, gat_w, a_src, a_dst, h16, asv, adv);
  k_gat_soft<<<dim3((NN+15)/16),256,0,stream>>>(rowptr, pks, asv, adv, coef);
  k_gat_agg<<<dim3(NN),128,0,stream>>>(rowptr, pks, coef, h16, gat_b, gout16);

  // ---- edge MLP ----
  k_AB<<<dim3(1500),64,0,stream>>>(gout16, Bt16, P);
  k_edge<<<dim3((EE+15)/16),256,0,stream>>>(ei, P, b1, w2, b2, out);
}

// Round 10
// 271.116 us; speedup vs baseline: 7.0352x; 1.0670x over previous
//
#include <hip/hip_runtime.h>
#include <math.h>

#define NN 6000
#define EE 100000
#define ELL (EE + NN)   // edges + self loops for GAT

// packed CSR entry: src (13b) | rel<<13 | self<<14
#define PK_SRC(p)  ((p) & 0x1FFF)
#define PK_REL(p)  (((p) >> 13) & 1)
#define PK_SELF(p) ((p) & 0x4000)

typedef __attribute__((ext_vector_type(8))) short frag8;           // 8 bf16 (4 VGPR)
typedef __attribute__((ext_vector_type(4))) float f32x4;
typedef __attribute__((ext_vector_type(8))) unsigned short u16x8;  // 16B of bf16

__device__ __forceinline__ unsigned short f2bf(float f){
  unsigned u = __float_as_uint(f);
  unsigned r = u + 0x7FFFu + ((u >> 16) & 1u);   // round-to-nearest-even
  return (unsigned short)(r >> 16);
}
__device__ __forceinline__ float bf2f(unsigned short s){
  return __uint_as_float(((unsigned)s) << 16);
}

// ---- fused: degree/count + weight prep (W0 bf16) + w1->Bt bf16 transpose ----
__global__ void k_pdc(const int* __restrict__ ei, const int* __restrict__ et,
                      int* __restrict__ deg, float* __restrict__ cnt,
                      const float* __restrict__ basis0, const float* __restrict__ comp0,
                      const float* __restrict__ b1,const float* __restrict__ c1,const float* __restrict__ r1,
                      const float* __restrict__ b2,const float* __restrict__ c2,const float* __restrict__ r2,
                      const float* __restrict__ b3,const float* __restrict__ c3,const float* __restrict__ r3,
                      const float* __restrict__ w1,
                      unsigned short* __restrict__ W016, float* __restrict__ Wcat,
                      unsigned short* __restrict__ Bt16){
  int t0 = blockIdx.x*256 + threadIdx.x;
  if (t0 < ELL){
    if (t0 < EE){
      int d = ei[EE+t0]; int r = et[t0];
      atomicAdd(&deg[d], 1);
      atomicAdd(&cnt[r*NN+d], 1.0f);
    } else {
      atomicAdd(&deg[t0-EE], 1);
    }
  }
  if (t0 < 2*NN*32){
    int r = t0 / (NN*32);
    int no = t0 - r*(NN*32);
    float acc = 0.f;
    #pragma unroll
    for (int b=0;b<4;b++) acc += comp0[r*4+b] * basis0[b*(NN*32)+no];
    W016[t0] = f2bf(acc);
    return;
  }
  int tw = t0 - 2*NN*32;
  if (tw < 24576){
    const float *bb,*cc,*rr; int I,O; int t = tw;
    if (tw < 6144)        { bb=b1;cc=c1;rr=r1;I=32;O=64; }
    else if (tw < 18432)  { bb=b2;cc=c2;rr=r2;I=64;O=64; t -= 6144; }
    else                  { bb=b3;cc=c3;rr=r3;I=64;O=32; t -= 18432; }
    int C = 3*O;
    int i = t / C; int col = t - i*C;
    float v;
    if (col < O) v = rr[i*O + col];
    else {
      int r = (col - O) / O; int o = col - O - r*O;
      v = 0.f;
      #pragma unroll
      for (int b=0;b<4;b++) v += cc[r*4+b]*bb[(b*I+i)*O + o];
    }
    Wcat[tw] = v;
    return;
  }
  int tb = tw - 24576;           // Bt16: [n][k], n in [0,256), k in [0,512)
  if (tb >= 256*512) return;
  int n = tb >> 9, k = tb & 511;
  float v = (n < 128) ? w1[k*128 + n] : w1[(512+k)*128 + (n-128)];
  Bt16[tb] = f2bf(v);
}

// single-block exclusive scan over NN=6000 (256 threads x 24 elements)
__global__ void k_scan(const int* __restrict__ deg, int* __restrict__ rowptr,
                       int* __restrict__ cursor){
  __shared__ int ssum[256];
  const int PER = 24;
  int tid = threadIdx.x;
  int base = tid*PER;
  int local[PER];
  int s = 0;
  #pragma unroll
  for (int k=0;k<PER;k++){ int i = base+k; int v = (i<NN)?deg[i]:0; local[k]=s; s+=v; }
  ssum[tid] = s; __syncthreads();
  for (int off=1; off<256; off<<=1){
    int v = (tid>=off) ? ssum[tid-off] : 0;
    __syncthreads();
    ssum[tid] += v;
    __syncthreads();
  }
  int prefix = (tid==0) ? 0 : ssum[tid-1];
  #pragma unroll
  for (int k=0;k<PER;k++){
    int i = base+k;
    if (i<NN){ int v = prefix+local[k]; rowptr[i]=v; cursor[i]=v; }
  }
  if (tid==255) rowptr[NN] = ssum[255];
}

// fill packed-src CSR
__global__ void k_fill(const int* __restrict__ ei, const int* __restrict__ et,
                       int* __restrict__ cursor, int* __restrict__ pks){
  int j = blockIdx.x*256 + threadIdx.x;
  if (j >= ELL) return;
  int d, pk;
  if (j < EE){ d = ei[EE+j]; pk = ei[j] | (et[j] << 13); }
  else       { d = j - EE;   pk = d | 0x4000; }
  int pos = atomicAdd(&cursor[d], 1);
  pks[pos] = pk;
}

// fused layer-0 aggregation + combine + tanh (x = I), W0 in bf16
__global__ void k_ragg0(const unsigned short* __restrict__ W016, const float* __restrict__ root,
                        const float* __restrict__ rbias,
                        const int* __restrict__ rowptr, const int* __restrict__ pks,
                        const float* __restrict__ cnt, float* __restrict__ xout){
  int n = blockIdx.x*8 + (threadIdx.x >> 5);
  int o = threadIdx.x & 31;
  if (n >= NN) return;
  int r0 = rowptr[n], r1 = rowptr[n+1];
  float a0 = 0.f, a1 = 0.f;
  for (int j=r0;j<r1;j++){
    int p = pks[j];
    if (PK_SELF(p)) continue;
    float v = bf2f(W016[(PK_REL(p)*NN + PK_SRC(p))*32 + o]);
    if (PK_REL(p)==0) a0 += v; else a1 += v;
  }
  float v = root[n*32+o] + rbias[o]
          + a0/fmaxf(cnt[n],1.f) + a1/fmaxf(cnt[NN+n],1.f);
  xout[n*32+o] = tanhf(v);
}

// H = x @ Wcat : [N, 3O] bf16 out — 8 nodes/block, 192 threads
template<int I>
__global__ void __launch_bounds__(192) k_nodemm(const float* __restrict__ x,
                                                const float* __restrict__ Wc,
                                                unsigned short* __restrict__ H16){
  __shared__ float sx[8*I];
  int n0 = blockIdx.x*8;
  for (int c = threadIdx.x; c < 8*I; c += 192) sx[c] = x[n0*I + c];
  __syncthreads();
  int c = threadIdx.x;      // 0..191
  float acc[8] = {0,0,0,0,0,0,0,0};
  for (int i=0;i<I;i++){
    float w = Wc[i*192 + c];
    #pragma unroll
    for (int tt=0;tt<8;tt++) acc[tt] += sx[tt*I + i] * w;
  }
  #pragma unroll
  for (int tt=0;tt<8;tt++) H16[(n0+tt)*192 + c] = f2bf(acc[tt]);
}

// fused RGCN agg + mean + root + tanh for layers 1..3 (H in bf16)
template<int O>
__global__ void k_ragg(const unsigned short* __restrict__ H16, const float* __restrict__ rbias,
                       const int* __restrict__ rowptr, const int* __restrict__ pks,
                       const float* __restrict__ cnt, float* __restrict__ xout){
  constexpr int NPB = 256/O;
  int n = blockIdx.x*NPB + threadIdx.x/O;
  int o = threadIdx.x % O;
  if (n >= NN) return;
  int r0 = rowptr[n], r1 = rowptr[n+1];
  float a0 = 0.f, a1 = 0.f;
  for (int j=r0;j<r1;j++){
    int p = pks[j];
    if (PK_SELF(p)) continue;
    int rel = PK_REL(p);
    float v = bf2f(H16[PK_SRC(p)*3*O + O + rel*O + o]);
    if (rel==0) a0 += v; else a1 += v;
  }
  float v = bf2f(H16[n*3*O + o]) + rbias[o]
          + a0/fmaxf(cnt[n],1.f) + a1/fmaxf(cnt[NN+n],1.f);
  xout[n*O+o] = tanhf(v);
}

// ---- GAT: h = x@gw (8 nodes/block) fused with per-node scores; h stored bf16 ----
__global__ void k_gat(const float* __restrict__ x, const float* __restrict__ gw,
                      const float* __restrict__ as_, const float* __restrict__ ad_,
                      unsigned short* __restrict__ h16,
                      float* __restrict__ asv, float* __restrict__ adv){
  int n0 = blockIdx.x*8;
  int t = threadIdx.x;  // 128 threads
  __shared__ float sx[8*32];
  __shared__ float red[2][16];
  for (int c=t; c<8*32; c+=128) sx[c] = x[n0*32 + c];
  __syncthreads();
  float4 acc[8];
  #pragma unroll
  for (int k=0;k<8;k++) acc[k] = {0,0,0,0};
  for (int i=0;i<32;i++){
    const float4 g = *(const float4*)&gw[i*512 + t*4];
    #pragma unroll
    for (int k=0;k<8;k++){
      float xv = sx[k*32+i];
      acc[k].x += xv*g.x; acc[k].y += xv*g.y; acc[k].z += xv*g.z; acc[k].w += xv*g.w;
    }
  }
  const float4 a4 = *(const float4*)&as_[t*4];
  const float4 d4 = *(const float4*)&ad_[t*4];
  float sa[8], sd[8];
  #pragma unroll
  for (int k=0;k<8;k++){
    ushort4 o;
    o.x = f2bf(acc[k].x); o.y = f2bf(acc[k].y);
    o.z = f2bf(acc[k].z); o.w = f2bf(acc[k].w);
    *(ushort4*)&h16[(n0+k)*512 + t*4] = o;
    sa[k] = acc[k].x*a4.x + acc[k].y*a4.y + acc[k].z*a4.z + acc[k].w*a4.w;
    sd[k] = acc[k].x*d4.x + acc[k].y*d4.y + acc[k].z*d4.z + acc[k].w*d4.w;
  }
  #pragma unroll
  for (int m=32;m>0;m>>=1){
    #pragma unroll
    for (int k=0;k<8;k++){ sa[k] += __shfl_xor(sa[k],m,64); sd[k] += __shfl_xor(sd[k],m,64); }
  }
  int wv = t>>6;
  if ((t&63)==0){
    #pragma unroll
    for (int k=0;k<8;k++){ red[wv][k]=sa[k]; red[wv][8+k]=sd[k]; }
  }
  __syncthreads();
  if (t<8)              asv[n0+t]   = red[0][t]+red[1][t];
  else if (t<16)        adv[n0+t-8] = red[0][t]+red[1][t];
}

// fused softmax + aggregation + bias + relu: 1 wave per node.
// Aggregate with un-normalized ex, scale by 1/sum at the end.
__global__ void __launch_bounds__(64) k_gsa(
    const int* __restrict__ rowptr, const int* __restrict__ pks,
    const float* __restrict__ asv, const float* __restrict__ adv,
    const unsigned short* __restrict__ h16, const float* __restrict__ bias,
    unsigned short* __restrict__ gout16){
  __shared__ float sex[64];
  __shared__ int  ssrc[64];
  int n = blockIdx.x;
  int lane = threadIdx.x;
  int r0 = rowptr[n], r1 = rowptr[n+1];
  float advn = adv[n];
  // pass 1: max over incident edges (self-loop guarantees deg >= 1)
  float m = -1e30f;
  for (int j = r0 + lane; j < r1; j += 64){
    float a = asv[PK_SRC(pks[j])] + advn; a = (a>=0.f)? a : 0.2f*a;
    m = fmaxf(m, a);
  }
  #pragma unroll
  for (int off=32;off>0;off>>=1) m = fmaxf(m, __shfl_xor(m,off,64));
  // pass 2: ex + aggregate, chunked by 64 edges
  float acc[8] = {0,0,0,0,0,0,0,0};
  float sumex = 0.f;
  for (int base = r0; base < r1; base += 64){
    int j = base + lane;
    float ex = 0.f; int src = 0;
    if (j < r1){
      int p = pks[j]; src = PK_SRC(p);
      float a = asv[src] + advn; a = (a>=0.f)? a : 0.2f*a;
      ex = expf(a - m);
      sumex += ex;
    }
    __syncthreads();
    sex[lane] = ex; ssrc[lane] = src;
    __syncthreads();
    int ce = min(64, r1 - base);
    for (int e = 0; e < ce; e++){
      float cf = sex[e];
      const u16x8 hv = *(const u16x8*)&h16[(size_t)ssrc[e]*512 + lane*8];
      #pragma unroll
      for (int q=0;q<8;q++) acc[q] += cf * bf2f(hv[q]);
    }
  }
  #pragma unroll
  for (int off=32;off>0;off>>=1) sumex += __shfl_xor(sumex,off,64);
  float inv = 1.f / fmaxf(sumex, 1e-16f);
  const float4 b0 = *(const float4*)&bias[lane*8];
  const float4 b1v = *(const float4*)&bias[lane*8+4];
  u16x8 o;
  o[0] = f2bf(fmaxf(acc[0]*inv + b0.x, 0.f));
  o[1] = f2bf(fmaxf(acc[1]*inv + b0.y, 0.f));
  o[2] = f2bf(fmaxf(acc[2]*inv + b0.z, 0.f));
  o[3] = f2bf(fmaxf(acc[3]*inv + b0.w, 0.f));
  o[4] = f2bf(fmaxf(acc[4]*inv + b1v.x, 0.f));
  o[5] = f2bf(fmaxf(acc[5]*inv + b1v.y, 0.f));
  o[6] = f2bf(fmaxf(acc[6]*inv + b1v.z, 0.f));
  o[7] = f2bf(fmaxf(acc[7]*inv + b1v.w, 0.f));
  *(u16x8*)&gout16[(size_t)n*512 + lane*8] = o;
}

// ---- edge MLP precompute via MFMA: P16[6000][256] = gout16 @ Bt16^T (bf16 out) ----
__global__ void __launch_bounds__(64) k_AB(const unsigned short* __restrict__ gout16,
                                           const unsigned short* __restrict__ Bt16,
                                           unsigned short* __restrict__ P16){
  int lane = threadIdx.x;
  int mt = blockIdx.x >> 2;        // 375 row tiles
  int nt = blockIdx.x & 3;         // 4 col groups of 64
  int kq = (lane >> 4) * 8;
  const unsigned short* arow = gout16 + (size_t)(mt*16 + (lane & 15))*512 + kq;
  const unsigned short* bbase = Bt16 + (size_t)(nt*64 + (lane & 15))*512 + kq;
  f32x4 acc0 = {0,0,0,0}, acc1 = {0,0,0,0}, acc2 = {0,0,0,0}, acc3 = {0,0,0,0};
  for (int k = 0; k < 512; k += 32){
    frag8 a = *(const frag8*)(arow + k);
    frag8 b0 = *(const frag8*)(bbase + k);
    frag8 b1 = *(const frag8*)(bbase + 16*512 + k);
    frag8 b2 = *(const frag8*)(bbase + 32*512 + k);
    frag8 b3 = *(const frag8*)(bbase + 48*512 + k);
    acc0 = __builtin_amdgcn_mfma_f32_16x16x32_bf16(a, b0, acc0, 0, 0, 0);
    acc1 = __builtin_amdgcn_mfma_f32_16x16x32_bf16(a, b1, acc1, 0, 0, 0);
    acc2 = __builtin_amdgcn_mfma_f32_16x16x32_bf16(a, b2, acc2, 0, 0, 0);
    acc3 = __builtin_amdgcn_mfma_f32_16x16x32_bf16(a, b3, acc3, 0, 0, 0);
  }
  int rowb = mt*16 + (lane >> 4)*4;
  int col  = nt*64 + (lane & 15);
  #pragma unroll
  for (int i=0;i<4;i++){
    P16[(size_t)(rowb+i)*256 + col     ] = f2bf(acc0[i]);
    P16[(size_t)(rowb+i)*256 + col + 16] = f2bf(acc1[i]);
    P16[(size_t)(rowb+i)*256 + col + 32] = f2bf(acc2[i]);
    P16[(size_t)(rowb+i)*256 + col + 48] = f2bf(acc3[i]);
  }
}

// per-edge MLP head: 16 lanes/edge, bf16 P loads
__global__ void k_edge(const int* __restrict__ ei, const unsigned short* __restrict__ P16,
                       const float* __restrict__ b1,
                       const float* __restrict__ w2, const float* __restrict__ b2,
                       float* __restrict__ out){
  int e = blockIdx.x*16 + (threadIdx.x >> 4);
  int l = threadIdx.x & 15;            // lane covers channels [l*8, l*8+8)
  if (e >= EE) return;
  int s = ei[e], d = ei[EE+e];
  const u16x8 Av = *(const u16x8*)&P16[(size_t)s*256 + l*8];
  const u16x8 Bv = *(const u16x8*)&P16[(size_t)d*256 + 128 + l*8];
  const float4 b1a = *(const float4*)&b1[l*8];
  const float4 b1b = *(const float4*)&b1[l*8+4];
  const float4 w2a = *(const float4*)&w2[l*8];
  const float4 w2b = *(const float4*)&w2[l*8+4];
  float h0 = fmaxf(bf2f(Av[0])+bf2f(Bv[0])+b1a.x, 0.f);
  float h1 = fmaxf(bf2f(Av[1])+bf2f(Bv[1])+b1a.y, 0.f);
  float h2 = fmaxf(bf2f(Av[2])+bf2f(Bv[2])+b1a.z, 0.f);
  float h3 = fmaxf(bf2f(Av[3])+bf2f(Bv[3])+b1a.w, 0.f);
  float h4 = fmaxf(bf2f(Av[4])+bf2f(Bv[4])+b1b.x, 0.f);
  float h5 = fmaxf(bf2f(Av[5])+bf2f(Bv[5])+b1b.y, 0.f);
  float h6 = fmaxf(bf2f(Av[6])+bf2f(Bv[6])+b1b.z, 0.f);
  float h7 = fmaxf(bf2f(Av[7])+bf2f(Bv[7])+b1b.w, 0.f);
  float acc = h0*w2a.x + h1*w2a.y + h2*w2a.z + h3*w2a.w
            + h4*w2b.x + h5*w2b.y + h6*w2b.z + h7*w2b.w;
  #pragma unroll
  for (int m=8;m>0;m>>=1) acc += __shfl_xor(acc,m,64);
  if (l==0) out[e] = 1.f/(1.f + expf(-(acc + b2[0])));
}

extern "C" void kernel_launch(void* const* d_in, const int* in_sizes, int n_in,
                              void* d_out, int out_size, void* d_ws, size_t ws_size,
                              hipStream_t stream){
  const float* basis0 = (const float*)d_in[0];
  const float* comp0  = (const float*)d_in[1];
  const float* root0  = (const float*)d_in[2];
  const float* rbias0 = (const float*)d_in[3];
  const float* basis1 = (const float*)d_in[4];
  const float* comp1  = (const float*)d_in[5];
  const float* root1  = (const float*)d_in[6];
  const float* rbias1 = (const float*)d_in[7];
  const float* basis2 = (const float*)d_in[8];
  const float* comp2  = (const float*)d_in[9];
  const float* root2  = (const float*)d_in[10];
  const float* rbias2 = (const float*)d_in[11];
  const float* basis3 = (const float*)d_in[12];
  const float* comp3  = (const float*)d_in[13];
  const float* root3  = (const float*)d_in[14];
  const float* rbias3 = (const float*)d_in[15];
  const float* gat_w = (const float*)d_in[16];
  const float* a_src = (const float*)d_in[17];
  const float* a_dst = (const float*)d_in[18];
  const float* gat_b = (const float*)d_in[19];
  const float* w1 = (const float*)d_in[20];
  const float* b1 = (const float*)d_in[21];
  const float* w2 = (const float*)d_in[22];
  const float* b2 = (const float*)d_in[23];
  const int* ei = (const int*)d_in[24];
  const int* et = (const int*)d_in[25];
  float* out = (float*)d_out;

  // workspace carve-up (all sections 16B-aligned; deg+cnt adjacent: one memset)
  float* p = (float*)d_ws;
  int* deg    = (int*)p; p += NN;              // 6000
  float* cnt  = p; p += 2*NN;                  // 12000
  int* rowptr = (int*)p; p += NN+4;            // 6004
  int* cursor = (int*)p; p += NN;              // 6000
  int* pks    = (int*)p; p += ELL + 4;         // 106004
  unsigned short* W016 = (unsigned short*)p; p += NN*32;       // 2*NN*32 bf16
  float* Wcat = p; p += 24576;
  unsigned short* Bt16 = (unsigned short*)p; p += 256*512/2;
  float* xa   = p; p += NN*64;
  float* xb   = p; p += NN*64;
  unsigned short* H16 = (unsigned short*)p; p += NN*96;        // NN*192 bf16
  unsigned short* h16 = (unsigned short*)p; p += NN*256;       // NN*512 bf16
  float* asv  = p; p += NN;
  float* adv  = p; p += NN;
  unsigned short* gout16 = (unsigned short*)p; p += NN*256;    // NN*512 bf16
  unsigned short* P16 = (unsigned short*)p; p += NN*128;       // NN*256 bf16

  auto grid = [](long long n){ return dim3((unsigned)((n + 255)/256)); };

  // ---- CSR build + weight prep + Bt16 (fused) ----
  hipMemsetAsync(deg, 0, (size_t)3*NN*sizeof(int), stream);  // deg + cnt
  k_pdc<<<grid(2LL*NN*32 + 24576 + 256*512),256,0,stream>>>(ei, et, deg, cnt,
        basis0, comp0, basis1,comp1,root1, basis2,comp2,root2,
        basis3,comp3,root3, w1, W016, Wcat, Bt16);
  k_scan<<<1,256,0,stream>>>(deg, rowptr, cursor);
  k_fill<<<grid(ELL),256,0,stream>>>(ei, et, cursor, pks);

  // ---- RGCN layer 0 (x = I) ----
  k_ragg0<<<dim3((NN+7)/8),256,0,stream>>>(W016, root0, rbias0, rowptr, pks, cnt, xa);

  // ---- RGCN layers 1..3 ----
  k_nodemm<32><<<dim3(750),192,0,stream>>>(xa, Wcat,         H16);
  k_ragg<64><<<dim3((NN+3)/4),256,0,stream>>>(H16, rbias1, rowptr, pks, cnt, xb);
  k_nodemm<64><<<dim3(750),192,0,stream>>>(xb, Wcat + 6144,  H16);
  k_ragg<64><<<dim3((NN+3)/4),256,0,stream>>>(H16, rbias2, rowptr, pks, cnt, xa);
  k_nodemm<64><<<dim3(750),192,0,stream>>>(xa, Wcat + 18432, H16);
  k_ragg<32><<<dim3((NN+7)/8),256,0,stream>>>(H16, rbias3, rowptr, pks, cnt, xb);
  // final RGCN output (N x 32) in xb

  // ---- GAT ----
  k_gat<<<dim3(NN/8),128,0,stream>>>(xb, gat_w, a_src, a_dst, h16, asv, adv);
  k_gsa<<<dim3(NN),64,0,stream>>>(rowptr, pks, asv, adv, h16, gat_b, gout16);

  // ---- edge MLP ----
  k_AB<<<dim3(1500),64,0,stream>>>(gout16, Bt16, P16);
  k_edge<<<dim3((EE+15)/16),256,0,stream>>>(ei, P16, b1, w2, b2, out);
}